// Round 1
// baseline (681.398 us; speedup 1.0000x reference)
//
#include <hip/hip_runtime.h>
#include <math.h>

#define EPSN 1e-12f

// ---------------- K0: per-token inverse L2 norm ----------------
// x layout: [b8=64][c=1024][s=64] ; token tm = b8*64 + s
__global__ void k0_tok_norm(const float* __restrict__ x, float* __restrict__ inv) {
  int b8 = blockIdx.x;            // 0..63
  int t = threadIdx.x;
  int s = t & 63, cg = t >> 6;
  const float* xp = x + (size_t)b8 * 65536;
  float acc = 0.f;
  for (int c = cg; c < 1024; c += 4) {
    float v = xp[c * 64 + s];
    acc = fmaf(v, v, acc);
  }
  __shared__ float red[256];
  red[t] = acc;
  __syncthreads();
  if (t < 64) {
    float ss = red[t] + red[t + 64] + red[t + 128] + red[t + 192];
    inv[b8 * 64 + t] = 1.0f / fmaxf(sqrtf(ss), EPSN);
  }
}

// ---------------- K1: transpose + scale -> xn[tm][c] ----------------
__global__ void k1_transpose(const float* __restrict__ x, const float* __restrict__ inv,
                             float* __restrict__ xn) {
  int ct = blockIdx.x;  // 0..15 (c tile of 64)
  int b8 = blockIdx.y;  // 0..63
  int t = threadIdx.x;
  __shared__ float tile[64][65];
  int s = t & 63, cq = t >> 6;
  const float* xp = x + (size_t)b8 * 65536 + (size_t)ct * 64 * 64;
#pragma unroll
  for (int r = 0; r < 16; ++r) {
    int cl = cq * 16 + r;
    tile[cl][s] = xp[cl * 64 + s];
  }
  __syncthreads();
  int cl = t & 63, sq = t >> 6;
#pragma unroll
  for (int r = 0; r < 16; ++r) {
    int ss = sq * 16 + r;
    int tm = b8 * 64 + ss;
    xn[(size_t)tm * 1024 + ct * 64 + cl] = tile[cl][ss] * inv[tm];
  }
}

// ---------------- K2/K4: fp32 NT GEMM, C[M,N] = A[M,K] * B[N,K]^T + bias ----------------
// BM=BN=128, BK=16, 256 threads, 8x8 microtile.
__launch_bounds__(256, 2)
__global__ void gemm_nt_f32(const float* __restrict__ A, const float* __restrict__ B,
                            const float* __restrict__ bias, float* __restrict__ C,
                            int K, int N) {
  __shared__ float As[16][132];
  __shared__ float Bs[16][132];
  int tid = threadIdx.x;
  int m0 = blockIdx.y * 128, n0 = blockIdx.x * 128;
  int tx = tid & 15, ty = tid >> 4;
  int lr = tid >> 2, lk = (tid & 3) << 2;
  const float* Ap = A + (size_t)(m0 + lr) * K + lk;
  const float* Bp = B + (size_t)(n0 + lr) * K + lk;
  size_t rstride = (size_t)64 * K;
  float acc[8][8];
#pragma unroll
  for (int i = 0; i < 8; ++i)
#pragma unroll
    for (int j = 0; j < 8; ++j) acc[i][j] = 0.f;

  for (int k0 = 0; k0 < K; k0 += 16) {
    float4 a0 = *(const float4*)(Ap + k0);
    float4 a1 = *(const float4*)(Ap + rstride + k0);
    float4 b0 = *(const float4*)(Bp + k0);
    float4 b1 = *(const float4*)(Bp + rstride + k0);
    As[lk + 0][lr] = a0.x; As[lk + 1][lr] = a0.y; As[lk + 2][lr] = a0.z; As[lk + 3][lr] = a0.w;
    As[lk + 0][lr + 64] = a1.x; As[lk + 1][lr + 64] = a1.y; As[lk + 2][lr + 64] = a1.z; As[lk + 3][lr + 64] = a1.w;
    Bs[lk + 0][lr] = b0.x; Bs[lk + 1][lr] = b0.y; Bs[lk + 2][lr] = b0.z; Bs[lk + 3][lr] = b0.w;
    Bs[lk + 0][lr + 64] = b1.x; Bs[lk + 1][lr + 64] = b1.y; Bs[lk + 2][lr + 64] = b1.z; Bs[lk + 3][lr + 64] = b1.w;
    __syncthreads();
#pragma unroll
    for (int k = 0; k < 16; ++k) {
      float4 va0 = *(const float4*)&As[k][ty << 2];
      float4 va1 = *(const float4*)&As[k][64 + (ty << 2)];
      float4 vb0 = *(const float4*)&Bs[k][tx << 2];
      float4 vb1 = *(const float4*)&Bs[k][64 + (tx << 2)];
      float a[8] = {va0.x, va0.y, va0.z, va0.w, va1.x, va1.y, va1.z, va1.w};
      float b[8] = {vb0.x, vb0.y, vb0.z, vb0.w, vb1.x, vb1.y, vb1.z, vb1.w};
#pragma unroll
      for (int i = 0; i < 8; ++i)
#pragma unroll
        for (int j = 0; j < 8; ++j)
          acc[i][j] = fmaf(a[i], b[j], acc[i][j]);
    }
    __syncthreads();
  }
  float4 bv0 = *(const float4*)&bias[n0 + (tx << 2)];
  float4 bv1 = *(const float4*)&bias[n0 + 64 + (tx << 2)];
#pragma unroll
  for (int i = 0; i < 8; ++i) {
    int row = m0 + (ty << 2) + (i & 3) + ((i >> 2) << 6);
    float4 o0 = {acc[i][0] + bv0.x, acc[i][1] + bv0.y, acc[i][2] + bv0.z, acc[i][3] + bv0.w};
    float4 o1 = {acc[i][4] + bv1.x, acc[i][5] + bv1.y, acc[i][6] + bv1.z, acc[i][7] + bv1.w};
    *(float4*)&C[(size_t)row * N + n0 + (tx << 2)] = o0;
    *(float4*)&C[(size_t)row * N + n0 + 64 + (tx << 2)] = o1;
  }
}

// ---------------- K3: alpha_g = sigmoid(Y @ W_g^T + b_g) ----------------
// 16 tokens/block, 16-thread teams, W_g (8x2048, 64KB) staged in LDS.
__global__ void k3_alpha_g(const float* __restrict__ Y, const float* __restrict__ Wg,
                           const float* __restrict__ bg, float* __restrict__ ag) {
  __shared__ float wgs[8 * 2048];
  int t = threadIdx.x;
  for (int r = 0; r < 64; ++r) wgs[t + r * 256] = Wg[t + r * 256];
  __syncthreads();
  int team = t >> 4, i = t & 15;
  int tok = blockIdx.x * 16 + team;
  const float* yp = Y + (size_t)tok * 2048;
  float acc[8] = {0, 0, 0, 0, 0, 0, 0, 0};
  for (int c0 = i * 4; c0 < 2048; c0 += 64) {
    float4 y4 = *(const float4*)&yp[c0];
#pragma unroll
    for (int g = 0; g < 8; ++g) {
      float4 w4 = *(const float4*)&wgs[g * 2048 + c0];
      acc[g] = fmaf(y4.x, w4.x, acc[g]);
      acc[g] = fmaf(y4.y, w4.y, acc[g]);
      acc[g] = fmaf(y4.z, w4.z, acc[g]);
      acc[g] = fmaf(y4.w, w4.w, acc[g]);
    }
  }
#pragma unroll
  for (int g = 0; g < 8; ++g) {
    acc[g] += __shfl_xor(acc[g], 1, 16);
    acc[g] += __shfl_xor(acc[g], 2, 16);
    acc[g] += __shfl_xor(acc[g], 4, 16);
    acc[g] += __shfl_xor(acc[g], 8, 16);
  }
  if (i < 8) {
    float v = 0.f;
#pragma unroll
    for (int g = 0; g < 8; ++g)
      if (g == i) v = acc[g];
    v += bg[i];
    ag[(size_t)tok * 8 + i] = 1.0f / (1.0f + expf(-v));
  }
}

// ---------------- K5: softmax over token dim (axis=1), in-place -> w_full ----------------
// Also writes colsumW[b][q] = sum_m w_full.
__global__ void k5_softmax(float* __restrict__ logits, const float* __restrict__ ag,
                           float* __restrict__ colsumW) {
  int qt = blockIdx.x;  // 0..15
  int b = blockIdx.y;   // 0..7
  int t = threadIdx.x;
  int ql = t & 63, mg = t >> 6;
  int q = qt * 64 + ql;
  int g = qt >> 1;  // block-uniform: 64 q's lie inside one g (K=128)
  float* lp = logits + (size_t)b * 512 * 1024 + q;
  __shared__ float red[256];
  __shared__ float colmax[64], colsum[64];
  float lmax = -1e30f;
  for (int m = mg; m < 512; m += 4) lmax = fmaxf(lmax, lp[(size_t)m * 1024]);
  red[t] = lmax;
  __syncthreads();
  if (mg == 0)
    colmax[ql] = fmaxf(fmaxf(red[ql], red[ql + 64]), fmaxf(red[ql + 128], red[ql + 192]));
  __syncthreads();
  float cm = colmax[ql];
  float s = 0.f;
  for (int m = mg; m < 512; m += 4) s += expf(lp[(size_t)m * 1024] - cm);
  red[t] = s;
  __syncthreads();
  if (mg == 0) colsum[ql] = red[ql] + red[ql + 64] + red[ql + 128] + red[ql + 192];
  __syncthreads();
  float rs = 1.0f / colsum[ql];
  float wsum = 0.f;
  const float* agp = ag + (size_t)b * 512 * 8 + g;
  for (int m = mg; m < 512; m += 4) {
    float w = expf(lp[(size_t)m * 1024] - cm) * rs * agp[(size_t)m * 8];
    lp[(size_t)m * 1024] = w;
    wsum += w;
  }
  red[t] = wsum;
  __syncthreads();
  if (mg == 0) colsumW[b * 1024 + q] = red[ql] + red[ql + 64] + red[ql + 128] + red[ql + 192];
}

// ---------------- K6: VLAD einsum partials ----------------
// block: 64k x 64d tile, m-chunk of 128, sum over g and m-chunk. 4x4 microtile.
__launch_bounds__(256, 2)
__global__ void k6_vlad(const float* __restrict__ Y, const float* __restrict__ wfull,
                        float* __restrict__ vpart) {
  int dt = blockIdx.x & 3;         // 0..3 (64 d)
  int kt = (blockIdx.x >> 2) & 1;  // 0..1 (64 k)
  int mc = blockIdx.y;             // 0..3 (128 m)
  int b = blockIdx.z;              // 0..7
  __shared__ float ly[32][64];
  __shared__ float lw[32][64];
  int t = threadIdx.x;
  int dq = t & 15, kq = t >> 4;
  float acc[4][4] = {};
  for (int g = 0; g < 8; ++g) {
    for (int sub = 0; sub < 4; ++sub) {
      __syncthreads();
      int col = t & 63, mq = t >> 6;
      int mbase = b * 512 + mc * 128 + sub * 32;
      const float* yp = Y + (size_t)(mbase + mq) * 2048 + g * 256 + dt * 64 + col;
      const float* wp = wfull + (size_t)(mbase + mq) * 1024 + g * 128 + kt * 64 + col;
#pragma unroll
      for (int r = 0; r < 8; ++r) {
        ly[mq + r * 4][col] = yp[(size_t)r * 4 * 2048];
        lw[mq + r * 4][col] = wp[(size_t)r * 4 * 1024];
      }
      __syncthreads();
#pragma unroll
      for (int mm = 0; mm < 32; ++mm) {
        float4 yv = *(const float4*)&ly[mm][dq * 4];
        float4 wv = *(const float4*)&lw[mm][kq * 4];
        acc[0][0] = fmaf(wv.x, yv.x, acc[0][0]); acc[0][1] = fmaf(wv.x, yv.y, acc[0][1]);
        acc[0][2] = fmaf(wv.x, yv.z, acc[0][2]); acc[0][3] = fmaf(wv.x, yv.w, acc[0][3]);
        acc[1][0] = fmaf(wv.y, yv.x, acc[1][0]); acc[1][1] = fmaf(wv.y, yv.y, acc[1][1]);
        acc[1][2] = fmaf(wv.y, yv.z, acc[1][2]); acc[1][3] = fmaf(wv.y, yv.w, acc[1][3]);
        acc[2][0] = fmaf(wv.z, yv.x, acc[2][0]); acc[2][1] = fmaf(wv.z, yv.y, acc[2][1]);
        acc[2][2] = fmaf(wv.z, yv.z, acc[2][2]); acc[2][3] = fmaf(wv.z, yv.w, acc[2][3]);
        acc[3][0] = fmaf(wv.w, yv.x, acc[3][0]); acc[3][1] = fmaf(wv.w, yv.y, acc[3][1]);
        acc[3][2] = fmaf(wv.w, yv.z, acc[3][2]); acc[3][3] = fmaf(wv.w, yv.w, acc[3][3]);
      }
    }
  }
  float* vp = vpart + ((size_t)mc * 8 + b) * 32768 + (size_t)(kt * 64) * 256 + dt * 64;
#pragma unroll
  for (int ki = 0; ki < 4; ++ki) {
    float4 o = {acc[ki][0], acc[ki][1], acc[ki][2], acc[ki][3]};
    *(float4*)&vp[(size_t)(kq * 4 + ki) * 256 + dq * 4] = o;
  }
}

// ---------------- K7: combine partials, subtract S*centroid, intra-normalize ----------------
__global__ void k7_intranorm(const float* __restrict__ vpart, const float* __restrict__ colsumW,
                             const float* __restrict__ cent, float* __restrict__ out,
                             float* __restrict__ ss1) {
  int k = blockIdx.x;   // 0..127
  int b = blockIdx.y;   // 0..7
  int d = threadIdx.x;  // 0..255
  float S = 0.f;
#pragma unroll
  for (int g = 0; g < 8; ++g) S += colsumW[b * 1024 + g * 128 + k];
  size_t off = (size_t)b * 32768 + (size_t)k * 256 + d;
  float v = vpart[off] + vpart[off + 262144] + vpart[off + 524288] + vpart[off + 786432]
            - S * cent[(size_t)k * 256 + d];
  float ss = v * v;
#pragma unroll
  for (int m = 1; m < 64; m <<= 1) ss += __shfl_xor(ss, m, 64);
  __shared__ float red[4];
  int lane = d & 63, w = d >> 6;
  if (lane == 0) red[w] = ss;
  __syncthreads();
  float tot = red[0] + red[1] + red[2] + red[3];
  float rinv = 1.0f / fmaxf(sqrtf(tot), EPSN);
  out[off] = v * rinv;
  if (d == 0) ss1[b * 128 + k] = tot * rinv * rinv;
}

// ---------------- K8: final global L2 norm over 32768 per batch ----------------
__global__ void k8_finalnorm(const float* __restrict__ ss1, float* __restrict__ out) {
  int b = blockIdx.x;
  int t = threadIdx.x;
  __shared__ float red[256];
  red[t] = (t < 128) ? ss1[b * 128 + t] : 0.f;
  __syncthreads();
  for (int off2 = 128; off2 > 0; off2 >>= 1) {
    if (t < off2) red[t] += red[t + off2];
    __syncthreads();
  }
  float rinv = 1.0f / fmaxf(sqrtf(red[0]), EPSN);
  float* op = out + (size_t)b * 32768;
  for (int i = t; i < 32768; i += 256) op[i] *= rinv;
}

extern "C" void kernel_launch(void* const* d_in, const int* in_sizes, int n_in,
                              void* d_out, int out_size, void* d_ws, size_t ws_size,
                              hipStream_t stream) {
  const float* x     = (const float*)d_in[0];
  const float* W_inp = (const float*)d_in[1];
  const float* b_inp = (const float*)d_in[2];
  const float* W_g   = (const float*)d_in[3];
  const float* b_g   = (const float*)d_in[4];
  const float* W_gk  = (const float*)d_in[5];
  const float* b_gk  = (const float*)d_in[6];
  const float* cent  = (const float*)d_in[7];
  float* out = (float*)d_out;
  float* ws = (float*)d_ws;

  // workspace layout (floats)
  float* inv     = ws;              // 4096
  float* colsumW = ws + 4096;       // 8192
  float* ss1     = ws + 12288;      // 1024
  float* ag      = ws + 13312;      // 32768
  float* xn      = ws + 65536;      // 4,194,304  (reused for logits -> w_full)
  float* Y       = ws + 4259840;    // 8,388,608
  float* vpart   = ws + 12648448;   // 1,048,576  (total ~54.8 MB)

  k0_tok_norm<<<64, 256, 0, stream>>>(x, inv);
  k1_transpose<<<dim3(16, 64), 256, 0, stream>>>(x, inv, xn);
  // GEMM1: Y[4096,2048] = xn[4096,1024] @ W_inp[2048,1024]^T + b_inp
  gemm_nt_f32<<<dim3(16, 32), 256, 0, stream>>>(xn, W_inp, b_inp, Y, 1024, 2048);
  k3_alpha_g<<<256, 256, 0, stream>>>(Y, W_g, b_g, ag);
  // GEMM2: logits[4096,1024] = Y[4096,2048] @ W_gk[1024,2048]^T + b_gk  (into xn buffer)
  gemm_nt_f32<<<dim3(8, 32), 256, 0, stream>>>(Y, W_gk, b_gk, xn, 2048, 1024);
  k5_softmax<<<dim3(16, 8), 256, 0, stream>>>(xn, ag, colsumW);
  k6_vlad<<<dim3(8, 4, 8), 256, 0, stream>>>(Y, xn, vpart);
  k7_intranorm<<<dim3(128, 8), 256, 0, stream>>>(vpart, colsumW, cent, out, ss1);
  k8_finalnorm<<<8, 256, 0, stream>>>(ss1, out);
}

// Round 2
// 320.071 us; speedup vs baseline: 2.1289x; 2.1289x over previous
//
#include <hip/hip_runtime.h>
#include <hip/hip_bf16.h>
#include <math.h>

#define EPSN 1e-12f

typedef float f32x4 __attribute__((ext_vector_type(4)));
typedef short s16x8 __attribute__((ext_vector_type(8)));
typedef unsigned short u16x8 __attribute__((ext_vector_type(8)));

__device__ __forceinline__ void gload_lds16(const void* g, void* l) {
  __builtin_amdgcn_global_load_lds((const __attribute__((address_space(1))) void*)g,
                                   (__attribute__((address_space(3))) void*)l, 16, 0, 0);
}

// ---------------- K0: per-token inverse L2 norm ----------------
__global__ void k0_tok_norm(const float* __restrict__ x, float* __restrict__ inv) {
  int b8 = blockIdx.x;
  int t = threadIdx.x;
  int s = t & 63, cg = t >> 6;
  const float* xp = x + (size_t)b8 * 65536;
  float acc = 0.f;
  for (int c = cg; c < 1024; c += 4) {
    float v = xp[c * 64 + s];
    acc = fmaf(v, v, acc);
  }
  __shared__ float red[256];
  red[t] = acc;
  __syncthreads();
  if (t < 64) {
    float ss = red[t] + red[t + 64] + red[t + 128] + red[t + 192];
    inv[b8 * 64 + t] = 1.0f / fmaxf(sqrtf(ss), EPSN);
  }
}

// ---------------- K1: transpose + scale -> xnb bf16 [tm][c] ----------------
__global__ void k1_transpose(const float* __restrict__ x, const float* __restrict__ inv,
                             __hip_bfloat16* __restrict__ xnb) {
  int ct = blockIdx.x;  // 0..15
  int b8 = blockIdx.y;  // 0..63
  int t = threadIdx.x;
  __shared__ float tile[64][65];
  int s = t & 63, cq = t >> 6;
  const float* xp = x + (size_t)b8 * 65536 + (size_t)ct * 64 * 64;
#pragma unroll
  for (int r = 0; r < 16; ++r) {
    int cl = cq * 16 + r;
    tile[cl][s] = xp[cl * 64 + s];
  }
  __syncthreads();
  int cl = t & 63, sq = t >> 6;
#pragma unroll
  for (int r = 0; r < 16; ++r) {
    int ss = sq * 16 + r;
    int tm = b8 * 64 + ss;
    xnb[(size_t)tm * 1024 + ct * 64 + cl] = __float2bfloat16(tile[cl][ss] * inv[tm]);
  }
}

// ---------------- pack fp32 -> bf16 ----------------
__global__ void kpack(const float* __restrict__ in, __hip_bfloat16* __restrict__ out, int n) {
  int i = (blockIdx.x * 256 + threadIdx.x) * 4;
  if (i < n) {
    float4 v = *(const float4*)(in + i);
    out[i + 0] = __float2bfloat16(v.x);
    out[i + 1] = __float2bfloat16(v.y);
    out[i + 2] = __float2bfloat16(v.z);
    out[i + 3] = __float2bfloat16(v.w);
  }
}

// ---------------- precompute bWgk[j] = b_inp @ W_gk[j,:] + b_gk[j]; bWg likewise ----------------
__global__ void kbw(const float* __restrict__ W_gk, const float* __restrict__ W_g,
                    const float* __restrict__ b_inp, const float* __restrict__ b_gk,
                    const float* __restrict__ b_g, float* __restrict__ bWgk,
                    float* __restrict__ bWg) {
  int j = blockIdx.x;
  const float* row;
  float bias;
  if (j < 1024) { row = W_gk + (size_t)j * 2048; bias = b_gk[j]; }
  else          { row = W_g + (size_t)(j - 1024) * 2048; bias = b_g[j - 1024]; }
  int t = threadIdx.x;
  float s = 0.f;
  for (int c = t; c < 2048; c += 256) s = fmaf(b_inp[c], row[c], s);
  __shared__ float red[256];
  red[t] = s;
  __syncthreads();
  for (int o = 128; o > 0; o >>= 1) {
    if (t < o) red[t] += red[t + o];
    __syncthreads();
  }
  if (t == 0) {
    float v = red[0] + bias;
    if (j < 1024) bWgk[j] = v; else bWg[j - 1024] = v;
  }
}

// ---------------- bf16 MFMA NT GEMM: C[M,N] = A[M,K] @ B[N,K]^T ----------------
// 128x128 tile, BK=32, 256 threads (4 waves, 2x2), 16x16x32 MFMA, global_load_lds.
template <bool OUT_BF16>
__launch_bounds__(256)
__global__ void gemm_bf16_nt(const __hip_bfloat16* __restrict__ A,
                             const __hip_bfloat16* __restrict__ B,
                             const float* __restrict__ biasv,
                             __hip_bfloat16* __restrict__ Cb, float* __restrict__ Cf,
                             int K, int N) {
  __shared__ alignas(16) __hip_bfloat16 Ash[128 * 32];
  __shared__ alignas(16) __hip_bfloat16 Bsh[128 * 32];
  const int tid = threadIdx.x;
  const int m0 = blockIdx.y * 128, n0 = blockIdx.x * 128;
  const int w = tid >> 6, l = tid & 63;
  const int wr = w >> 1, wc = w & 1;
  const int srow = tid >> 2;
  const int sk = (tid & 3) * 8;
  const __hip_bfloat16* Ag = A + (size_t)(m0 + srow) * K + sk;
  const __hip_bfloat16* Bg = B + (size_t)(n0 + srow) * K + sk;
  const size_t r64 = (size_t)64 * K;
  __hip_bfloat16* ldsA0 = Ash + w * 512;
  __hip_bfloat16* ldsA1 = Ash + 2048 + w * 512;
  __hip_bfloat16* ldsB0 = Bsh + w * 512;
  __hip_bfloat16* ldsB1 = Bsh + 2048 + w * 512;

  f32x4 acc[4][4];
#pragma unroll
  for (int i = 0; i < 4; ++i)
#pragma unroll
    for (int j = 0; j < 4; ++j) acc[i][j] = (f32x4){0.f, 0.f, 0.f, 0.f};

  for (int k0 = 0; k0 < K; k0 += 32) {
    gload_lds16(Ag + k0, ldsA0);
    gload_lds16(Ag + r64 + k0, ldsA1);
    gload_lds16(Bg + k0, ldsB0);
    gload_lds16(Bg + r64 + k0, ldsB1);
    __syncthreads();
    s16x8 af[4], bfr[4];
#pragma unroll
    for (int mi = 0; mi < 4; ++mi) {
      af[mi]  = *(const s16x8*)(Ash + (wr * 64 + mi * 16 + (l & 15)) * 32 + (l >> 4) * 8);
      bfr[mi] = *(const s16x8*)(Bsh + (wc * 64 + mi * 16 + (l & 15)) * 32 + (l >> 4) * 8);
    }
#pragma unroll
    for (int mi = 0; mi < 4; ++mi)
#pragma unroll
      for (int ni = 0; ni < 4; ++ni)
        acc[mi][ni] = __builtin_amdgcn_mfma_f32_16x16x32_bf16(af[mi], bfr[ni], acc[mi][ni], 0, 0, 0);
    __syncthreads();
  }

#pragma unroll
  for (int mi = 0; mi < 4; ++mi) {
    int row = m0 + wr * 64 + mi * 16 + (l >> 4) * 4;
#pragma unroll
    for (int ni = 0; ni < 4; ++ni) {
      int col = n0 + wc * 64 + ni * 16 + (l & 15);
#pragma unroll
      for (int r = 0; r < 4; ++r) {
        if constexpr (OUT_BF16)
          Cb[(size_t)(row + r) * N + col] = __float2bfloat16(acc[mi][ni][r]);
        else
          Cf[(size_t)(row + r) * N + col] = acc[mi][ni][r] + biasv[col];
      }
    }
  }
}

// ---------------- K3: alpha_g = sigmoid(Yc @ W_g^T + bWg) ----------------
__global__ void k3_alpha_g(const __hip_bfloat16* __restrict__ Yc, const float* __restrict__ Wg,
                           const float* __restrict__ bWg, float* __restrict__ ag) {
  __shared__ float wgs[8 * 2048];
  int t = threadIdx.x;
  for (int r = 0; r < 64; ++r) wgs[t + r * 256] = Wg[t + r * 256];
  __syncthreads();
  int team = t >> 4, i = t & 15;
  int tok = blockIdx.x * 16 + team;
  const __hip_bfloat16* yp = Yc + (size_t)tok * 2048;
  float acc[8] = {0, 0, 0, 0, 0, 0, 0, 0};
  for (int c0 = i * 8; c0 < 2048; c0 += 128) {
    u16x8 y8 = *(const u16x8*)(yp + c0);
#pragma unroll
    for (int j = 0; j < 8; ++j) {
      float yf = __uint_as_float(((unsigned)y8[j]) << 16);
#pragma unroll
      for (int g = 0; g < 8; ++g)
        acc[g] = fmaf(yf, wgs[g * 2048 + c0 + j], acc[g]);
    }
  }
#pragma unroll
  for (int g = 0; g < 8; ++g) {
    acc[g] += __shfl_xor(acc[g], 1, 16);
    acc[g] += __shfl_xor(acc[g], 2, 16);
    acc[g] += __shfl_xor(acc[g], 4, 16);
    acc[g] += __shfl_xor(acc[g], 8, 16);
  }
  if (i < 8) {
    float v = 0.f;
#pragma unroll
    for (int g = 0; g < 8; ++g)
      if (g == i) v = acc[g];
    v += bWg[i];
    ag[(size_t)tok * 8 + i] = 1.0f / (1.0f + expf(-v));
  }
}

// ---------------- K5: softmax over token dim, in-place -> w_full ----------------
__global__ void k5_softmax(float* __restrict__ logits, const float* __restrict__ ag,
                           float* __restrict__ colsumW) {
  int qt = blockIdx.x;
  int b = blockIdx.y;
  int t = threadIdx.x;
  int ql = t & 63, mg = t >> 6;
  int q = qt * 64 + ql;
  int g = qt >> 1;
  float* lp = logits + (size_t)b * 512 * 1024 + q;
  __shared__ float red[256];
  __shared__ float colmax[64], colsum[64];
  float lmax = -1e30f;
  for (int m = mg; m < 512; m += 4) lmax = fmaxf(lmax, lp[(size_t)m * 1024]);
  red[t] = lmax;
  __syncthreads();
  if (mg == 0)
    colmax[ql] = fmaxf(fmaxf(red[ql], red[ql + 64]), fmaxf(red[ql + 128], red[ql + 192]));
  __syncthreads();
  float cm = colmax[ql];
  float s = 0.f;
  for (int m = mg; m < 512; m += 4) s += expf(lp[(size_t)m * 1024] - cm);
  red[t] = s;
  __syncthreads();
  if (mg == 0) colsum[ql] = red[ql] + red[ql + 64] + red[ql + 128] + red[ql + 192];
  __syncthreads();
  float rs = 1.0f / colsum[ql];
  float wsum = 0.f;
  const float* agp = ag + (size_t)b * 512 * 8 + g;
  for (int m = mg; m < 512; m += 4) {
    float w = expf(lp[(size_t)m * 1024] - cm) * rs * agp[(size_t)m * 8];
    lp[(size_t)m * 1024] = w;
    wsum += w;
  }
  red[t] = wsum;
  __syncthreads();
  if (mg == 0) colsumW[b * 1024 + q] = red[ql] + red[ql + 64] + red[ql + 128] + red[ql + 192];
}

// ---------------- K6: VLAD einsum partials (w @ Yc part) ----------------
__launch_bounds__(256, 2)
__global__ void k6_vlad(const __hip_bfloat16* __restrict__ Ycb, const float* __restrict__ wfull,
                        float* __restrict__ vpart) {
  int dt = blockIdx.x & 3;
  int kt = (blockIdx.x >> 2) & 1;
  int mc = blockIdx.y;
  int b = blockIdx.z;
  __shared__ float ly[32][64];
  __shared__ float lw[32][64];
  int t = threadIdx.x;
  int dq = t & 15, kq = t >> 4;
  float acc[4][4] = {};
  const unsigned short* Yu = (const unsigned short*)Ycb;
  for (int g = 0; g < 8; ++g) {
    for (int sub = 0; sub < 4; ++sub) {
      __syncthreads();
      int col = t & 63, mq = t >> 6;
      int mbase = b * 512 + mc * 128 + sub * 32;
      const unsigned short* yp = Yu + (size_t)(mbase + mq) * 2048 + g * 256 + dt * 64 + col;
      const float* wp = wfull + (size_t)(mbase + mq) * 1024 + g * 128 + kt * 64 + col;
#pragma unroll
      for (int r = 0; r < 8; ++r) {
        ly[mq + r * 4][col] = __uint_as_float(((unsigned)yp[(size_t)r * 4 * 2048]) << 16);
        lw[mq + r * 4][col] = wp[(size_t)r * 4 * 1024];
      }
      __syncthreads();
#pragma unroll
      for (int mm = 0; mm < 32; ++mm) {
        float4 yv = *(const float4*)&ly[mm][dq * 4];
        float4 wv = *(const float4*)&lw[mm][kq * 4];
        acc[0][0] = fmaf(wv.x, yv.x, acc[0][0]); acc[0][1] = fmaf(wv.x, yv.y, acc[0][1]);
        acc[0][2] = fmaf(wv.x, yv.z, acc[0][2]); acc[0][3] = fmaf(wv.x, yv.w, acc[0][3]);
        acc[1][0] = fmaf(wv.y, yv.x, acc[1][0]); acc[1][1] = fmaf(wv.y, yv.y, acc[1][1]);
        acc[1][2] = fmaf(wv.y, yv.z, acc[1][2]); acc[1][3] = fmaf(wv.y, yv.w, acc[1][3]);
        acc[2][0] = fmaf(wv.z, yv.x, acc[2][0]); acc[2][1] = fmaf(wv.z, yv.y, acc[2][1]);
        acc[2][2] = fmaf(wv.z, yv.z, acc[2][2]); acc[2][3] = fmaf(wv.z, yv.w, acc[2][3]);
        acc[3][0] = fmaf(wv.w, yv.x, acc[3][0]); acc[3][1] = fmaf(wv.w, yv.y, acc[3][1]);
        acc[3][2] = fmaf(wv.w, yv.z, acc[3][2]); acc[3][3] = fmaf(wv.w, yv.w, acc[3][3]);
      }
    }
  }
  float* vp = vpart + ((size_t)mc * 8 + b) * 32768 + (size_t)(kt * 64) * 256 + dt * 64;
#pragma unroll
  for (int ki = 0; ki < 4; ++ki) {
    float4 o = {acc[ki][0], acc[ki][1], acc[ki][2], acc[ki][3]};
    *(float4*)&vp[(size_t)(kq * 4 + ki) * 256 + dq * 4] = o;
  }
}

// ---------------- K7: combine partials + bias-part - S*centroid, intra-normalize ----------------
__global__ void k7_intranorm(const float* __restrict__ vpart, const float* __restrict__ colsumW,
                             const float* __restrict__ b_inp, const float* __restrict__ cent,
                             float* __restrict__ out, float* __restrict__ ss1) {
  int k = blockIdx.x;
  int b = blockIdx.y;
  int d = threadIdx.x;
  float S = 0.f, bp = 0.f;
#pragma unroll
  for (int g = 0; g < 8; ++g) {
    float cw = colsumW[b * 1024 + g * 128 + k];
    S += cw;
    bp = fmaf(b_inp[g * 256 + d], cw, bp);
  }
  size_t off = (size_t)b * 32768 + (size_t)k * 256 + d;
  float v = vpart[off] + vpart[off + 262144] + vpart[off + 524288] + vpart[off + 786432]
            + bp - S * cent[(size_t)k * 256 + d];
  float ss = v * v;
#pragma unroll
  for (int m = 1; m < 64; m <<= 1) ss += __shfl_xor(ss, m, 64);
  __shared__ float red[4];
  int lane = d & 63, wv = d >> 6;
  if (lane == 0) red[wv] = ss;
  __syncthreads();
  float tot = red[0] + red[1] + red[2] + red[3];
  float rinv = 1.0f / fmaxf(sqrtf(tot), EPSN);
  out[off] = v * rinv;
  if (d == 0) ss1[b * 128 + k] = tot * rinv * rinv;
}

// ---------------- K8: final global L2 norm ----------------
__global__ void k8_finalnorm(const float* __restrict__ ss1, float* __restrict__ out) {
  int b = blockIdx.x;
  int t = threadIdx.x;
  __shared__ float red[256];
  red[t] = (t < 128) ? ss1[b * 128 + t] : 0.f;
  __syncthreads();
  for (int o = 128; o > 0; o >>= 1) {
    if (t < o) red[t] += red[t + o];
    __syncthreads();
  }
  float rinv = 1.0f / fmaxf(sqrtf(red[0]), EPSN);
  float* op = out + (size_t)b * 32768;
  for (int i = t; i < 32768; i += 256) op[i] *= rinv;
}

extern "C" void kernel_launch(void* const* d_in, const int* in_sizes, int n_in,
                              void* d_out, int out_size, void* d_ws, size_t ws_size,
                              hipStream_t stream) {
  const float* x     = (const float*)d_in[0];
  const float* W_inp = (const float*)d_in[1];
  const float* b_inp = (const float*)d_in[2];
  const float* W_g   = (const float*)d_in[3];
  const float* b_g   = (const float*)d_in[4];
  const float* W_gk  = (const float*)d_in[5];
  const float* b_gk  = (const float*)d_in[6];
  const float* cent  = (const float*)d_in[7];
  float* out = (float*)d_out;
  float* ws = (float*)d_ws;

  // workspace layout (float offsets), total ~54.7 MB
  float* inv     = ws + 0;        // 4096
  float* colsumW = ws + 4096;     // 8192
  float* ss1     = ws + 12288;    // 1024
  float* ag      = ws + 13312;    // 32768
  float* bWgk    = ws + 46080;    // 1024
  float* bWg     = ws + 47104;    // 8 (pad 64)
  float* vpart   = ws + 47168;    // 1048576
  float* logits  = ws + 1095744;  // 4194304 (reused in-place as w_full)
  __hip_bfloat16* xnb  = (__hip_bfloat16*)(ws + 5290048);  // 4096x1024 bf16
  __hip_bfloat16* Wib  = (__hip_bfloat16*)(ws + 7387200);  // 2048x1024 bf16
  __hip_bfloat16* Wgkb = (__hip_bfloat16*)(ws + 8435776);  // 1024x2048 bf16
  __hip_bfloat16* Ycb  = (__hip_bfloat16*)(ws + 9484352);  // 4096x2048 bf16

  k0_tok_norm<<<64, 256, 0, stream>>>(x, inv);
  k1_transpose<<<dim3(16, 64), 256, 0, stream>>>(x, inv, xnb);
  kpack<<<2048, 256, 0, stream>>>(W_inp, Wib, 2097152);
  kpack<<<2048, 256, 0, stream>>>(W_gk, Wgkb, 2097152);
  kbw<<<1032, 256, 0, stream>>>(W_gk, W_g, b_inp, b_gk, b_g, bWgk, bWg);
  // GEMM1: Ycb[4096,2048] = xnb @ Wib^T   (centered: no bias)
  gemm_bf16_nt<true><<<dim3(16, 32), 256, 0, stream>>>(xnb, Wib, nullptr, Ycb, nullptr, 1024, 2048);
  k3_alpha_g<<<256, 256, 0, stream>>>(Ycb, W_g, bWg, ag);
  // GEMM2: logits[4096,1024] = Ycb @ Wgkb^T + bWgk
  gemm_bf16_nt<false><<<dim3(8, 32), 256, 0, stream>>>(Ycb, Wgkb, bWgk, nullptr, logits, 2048, 1024);
  k5_softmax<<<dim3(16, 8), 256, 0, stream>>>(logits, ag, colsumW);
  k6_vlad<<<dim3(8, 4, 8), 256, 0, stream>>>(Ycb, logits, vpart);
  k7_intranorm<<<dim3(128, 8), 256, 0, stream>>>(vpart, colsumW, b_inp, cent, out, ss1);
  k8_finalnorm<<<8, 256, 0, stream>>>(ss1, out);
}

// Round 3
// 224.070 us; speedup vs baseline: 3.0410x; 1.4284x over previous
//
#include <hip/hip_runtime.h>
#include <hip/hip_bf16.h>
#include <math.h>

#define EPSN 1e-12f
typedef unsigned short ushort_t;

typedef float f32x4 __attribute__((ext_vector_type(4)));
typedef short s16x8 __attribute__((ext_vector_type(8)));
typedef unsigned short u16x8 __attribute__((ext_vector_type(8)));

__device__ __forceinline__ void gload_lds16(const void* g, void* l) {
  __builtin_amdgcn_global_load_lds((const __attribute__((address_space(1))) void*)g,
                                   (__attribute__((address_space(3))) void*)l, 16, 0, 0);
}

// ---------------- K0: per-token sum of squares (atomic partials) ----------------
// x layout: [b8=64][c=1024][s=64]; token tm = b8*64 + s. 512 blocks.
__global__ void k0_ssq(const float* __restrict__ x, float* __restrict__ ssq) {
  int b8 = blockIdx.x >> 3;
  int cc = blockIdx.x & 7;  // 128-c chunk
  int t = threadIdx.x;
  int s4 = (t & 15) * 4;
  int cg = t >> 4;  // 0..15
  const float* xp = x + (size_t)b8 * 65536 + (size_t)cc * 128 * 64;
  float4 a = {0.f, 0.f, 0.f, 0.f};
#pragma unroll
  for (int j = 0; j < 8; ++j) {
    int c = cg + j * 16;
    float4 v = *(const float4*)(xp + (size_t)c * 64 + s4);
    a.x = fmaf(v.x, v.x, a.x);
    a.y = fmaf(v.y, v.y, a.y);
    a.z = fmaf(v.z, v.z, a.z);
    a.w = fmaf(v.w, v.w, a.w);
  }
  __shared__ float red[16][68];
  *(float4*)&red[cg][s4] = a;
  __syncthreads();
  if (t < 64) {
    float s = 0.f;
#pragma unroll
    for (int g = 0; g < 16; ++g) s += red[g][t];
    atomicAdd(&ssq[b8 * 64 + t], s);
  }
}

// ---------------- K1: transpose + scale -> xnb bf16 [tm][c] ----------------
__global__ void k1_transpose(const float* __restrict__ x, const float* __restrict__ ssq,
                             __hip_bfloat16* __restrict__ xnb) {
  int ct = blockIdx.x;  // 0..15
  int b8 = blockIdx.y;  // 0..63
  int t = threadIdx.x;
  __shared__ float tile[64][65];
  int s = t & 63, cq = t >> 6;
  const float* xp = x + (size_t)b8 * 65536 + (size_t)ct * 64 * 64;
#pragma unroll
  for (int r = 0; r < 16; ++r) {
    int cl = cq * 16 + r;
    tile[cl][s] = xp[cl * 64 + s];
  }
  __syncthreads();
  int cl = t & 63, sq = t >> 6;
#pragma unroll
  for (int r = 0; r < 16; ++r) {
    int smm = sq * 16 + r;
    int tm = b8 * 64 + smm;
    float iv = rsqrtf(fmaxf(ssq[tm], 1e-24f));
    xnb[(size_t)tm * 1024 + ct * 64 + cl] = __float2bfloat16(tile[cl][smm] * iv);
  }
}

// ---------------- pack fp32 -> bf16 ----------------
__global__ void kpack(const float* __restrict__ in, __hip_bfloat16* __restrict__ out, int n) {
  int i = (blockIdx.x * 256 + threadIdx.x) * 4;
  if (i < n) {
    float4 v = *(const float4*)(in + i);
    out[i + 0] = __float2bfloat16(v.x);
    out[i + 1] = __float2bfloat16(v.y);
    out[i + 2] = __float2bfloat16(v.z);
    out[i + 3] = __float2bfloat16(v.w);
  }
}

// ---------------- bWg[j] = b_inp @ W_g[j,:] + b_g[j] (8 rows) ----------------
__global__ void kbw(const float* __restrict__ W_g, const float* __restrict__ b_inp,
                    const float* __restrict__ b_g, float* __restrict__ bWg) {
  int j = blockIdx.x;  // 0..7
  const float* row = W_g + (size_t)j * 2048;
  int t = threadIdx.x;
  float s = 0.f;
  for (int c = t; c < 2048; c += 256) s = fmaf(b_inp[c], row[c], s);
  __shared__ float red[256];
  red[t] = s;
  __syncthreads();
  for (int o = 128; o > 0; o >>= 1) {
    if (t < o) red[t] += red[t + o];
    __syncthreads();
  }
  if (t == 0) bWg[j] = red[0] + b_g[j];
}

// ---------------- bf16 MFMA NT GEMM: C[M,N] = A[M,K] @ B[N,K]^T ----------------
// 128x128 tile, BK=32, 256 threads (4 waves, 2x2), 16x16x32 MFMA, global_load_lds.
// OUT: 0 = bf16, 1 = f32
template <int OUT>
__launch_bounds__(256)
__global__ void gemm_bf16_nt(const __hip_bfloat16* __restrict__ A,
                             const __hip_bfloat16* __restrict__ B,
                             __hip_bfloat16* __restrict__ Cb, float* __restrict__ Cf,
                             int K, int N) {
  __shared__ alignas(16) __hip_bfloat16 Ash[128 * 32];
  __shared__ alignas(16) __hip_bfloat16 Bsh[128 * 32];
  const int tid = threadIdx.x;
  const int m0 = blockIdx.y * 128, n0 = blockIdx.x * 128;
  const int w = tid >> 6, l = tid & 63;
  const int wr = w >> 1, wc = w & 1;
  const int srow = tid >> 2;
  const int sk = (tid & 3) * 8;
  const __hip_bfloat16* Ag = A + (size_t)(m0 + srow) * K + sk;
  const __hip_bfloat16* Bg = B + (size_t)(n0 + srow) * K + sk;
  const size_t r64 = (size_t)64 * K;
  __hip_bfloat16* ldsA0 = Ash + w * 512;
  __hip_bfloat16* ldsA1 = Ash + 2048 + w * 512;
  __hip_bfloat16* ldsB0 = Bsh + w * 512;
  __hip_bfloat16* ldsB1 = Bsh + 2048 + w * 512;

  f32x4 acc[4][4];
#pragma unroll
  for (int i = 0; i < 4; ++i)
#pragma unroll
    for (int j = 0; j < 4; ++j) acc[i][j] = (f32x4){0.f, 0.f, 0.f, 0.f};

  for (int k0 = 0; k0 < K; k0 += 32) {
    gload_lds16(Ag + k0, ldsA0);
    gload_lds16(Ag + r64 + k0, ldsA1);
    gload_lds16(Bg + k0, ldsB0);
    gload_lds16(Bg + r64 + k0, ldsB1);
    __syncthreads();
    s16x8 af[4], bfr[4];
#pragma unroll
    for (int mi = 0; mi < 4; ++mi) {
      af[mi]  = *(const s16x8*)(Ash + (wr * 64 + mi * 16 + (l & 15)) * 32 + (l >> 4) * 8);
      bfr[mi] = *(const s16x8*)(Bsh + (wc * 64 + mi * 16 + (l & 15)) * 32 + (l >> 4) * 8);
    }
#pragma unroll
    for (int mi = 0; mi < 4; ++mi)
#pragma unroll
      for (int ni = 0; ni < 4; ++ni)
        acc[mi][ni] = __builtin_amdgcn_mfma_f32_16x16x32_bf16(af[mi], bfr[ni], acc[mi][ni], 0, 0, 0);
    __syncthreads();
  }

#pragma unroll
  for (int mi = 0; mi < 4; ++mi) {
    int row = m0 + wr * 64 + mi * 16 + (l >> 4) * 4;
#pragma unroll
    for (int ni = 0; ni < 4; ++ni) {
      int col = n0 + wc * 64 + ni * 16 + (l & 15);
#pragma unroll
      for (int r = 0; r < 4; ++r) {
        if constexpr (OUT == 0)
          Cb[(size_t)(row + r) * N + col] = __float2bfloat16(acc[mi][ni][r]);
        else
          Cf[(size_t)(row + r) * N + col] = acc[mi][ni][r];
      }
    }
  }
}

// ---------------- K3: alpha_g = sigmoid(Yc @ W_g^T + bWg) ----------------
__global__ void k3_alpha_g(const __hip_bfloat16* __restrict__ Yc, const float* __restrict__ Wg,
                           const float* __restrict__ bWg, float* __restrict__ ag) {
  __shared__ float wgs[8 * 2048];
  int t = threadIdx.x;
  for (int r = 0; r < 64; ++r) wgs[t + r * 256] = Wg[t + r * 256];
  __syncthreads();
  int team = t >> 4, i = t & 15;
  int tok = blockIdx.x * 16 + team;
  const __hip_bfloat16* yp = Yc + (size_t)tok * 2048;
  float acc[8] = {0, 0, 0, 0, 0, 0, 0, 0};
  for (int c0 = i * 8; c0 < 2048; c0 += 128) {
    u16x8 y8 = *(const u16x8*)(yp + c0);
#pragma unroll
    for (int j = 0; j < 8; ++j) {
      float yf = __uint_as_float(((unsigned)y8[j]) << 16);
#pragma unroll
      for (int g = 0; g < 8; ++g)
        acc[g] = fmaf(yf, wgs[g * 2048 + c0 + j], acc[g]);
    }
  }
#pragma unroll
  for (int g = 0; g < 8; ++g) {
    acc[g] += __shfl_xor(acc[g], 1, 16);
    acc[g] += __shfl_xor(acc[g], 2, 16);
    acc[g] += __shfl_xor(acc[g], 4, 16);
    acc[g] += __shfl_xor(acc[g], 8, 16);
  }
  if (i < 8) {
    float v = 0.f;
#pragma unroll
    for (int g = 0; g < 8; ++g)
      if (g == i) v = acc[g];
    v += bWg[i];
    ag[(size_t)tok * 8 + i] = 1.0f / (1.0f + expf(-v));
  }
}

// ---------------- K5: softmax over token dim -> wT bf16 [b][q][m] + colsumW ----------------
// 512 threads, 2-pass (online max/sum, then normalize*ag), LDS transposed tile.
__launch_bounds__(512)
__global__ void k5_softmax(const float* __restrict__ logits, const float* __restrict__ ag,
                           float* __restrict__ colsumW, ushort_t* __restrict__ wT) {
  int qt = blockIdx.x;  // 0..15
  int b = blockIdx.y;   // 0..7
  int t = threadIdx.x;
  int ql = t & 63, mg = t >> 6;  // mg 0..7
  int q = qt * 64 + ql;
  int g = qt >> 1;
  const float* lp = logits + (size_t)b * 524288 + q;
  __shared__ float rmx[8][72], rsm[8][72];
  __shared__ float cmx[64], crs[64];
  __shared__ ushort_t wt[64][514];  // stride 514: conflict-free column writes

  float mx = -1e30f, sm = 0.f;
  for (int m = mg; m < 512; m += 8) {
    float v = lp[(size_t)m * 1024];
    if (v <= mx) {
      sm += expf(v - mx);
    } else {
      sm = sm * expf(mx - v) + 1.f;
      mx = v;
    }
  }
  rmx[mg][ql] = mx;
  rsm[mg][ql] = sm;
  __syncthreads();
  if (t < 64) {
    float M = rmx[0][ql];
#pragma unroll
    for (int i = 1; i < 8; ++i) M = fmaxf(M, rmx[i][ql]);
    float S = 0.f;
#pragma unroll
    for (int i = 0; i < 8; ++i) S += rsm[i][ql] * expf(rmx[i][ql] - M);
    cmx[ql] = M;
    crs[ql] = 1.0f / S;
  }
  __syncthreads();
  float M = cmx[ql], R = crs[ql];
  const float* agp = ag + (size_t)b * 4096 + g;
  float wsum = 0.f;
  for (int m = mg; m < 512; m += 8) {
    float wv = expf(lp[(size_t)m * 1024] - M) * R * agp[(size_t)m * 8];
    __hip_bfloat16 hb = __float2bfloat16(wv);
    wt[ql][m] = *(ushort_t*)&hb;
    wsum += wv;
  }
  rsm[mg][ql] = wsum;
  __syncthreads();
  if (t < 64) {
    float S = 0.f;
#pragma unroll
    for (int i = 0; i < 8; ++i) S += rsm[i][ql];
    colsumW[b * 1024 + q] = S;
  }
  __syncthreads();
  // coalesced write-out of wT rows
  int row = t >> 3, seg = (t & 7) * 64;
  ushort_t* dst = wT + ((size_t)b * 1024 + (size_t)qt * 64 + row) * 512 + seg;
  const ushort_t* src = &wt[row][seg];
#pragma unroll
  for (int j = 0; j < 8; ++j) {
    u16x8 o;
#pragma unroll
    for (int p = 0; p < 4; ++p) {
      unsigned v = *(const unsigned*)(src + j * 8 + p * 2);
      o[p * 2] = (ushort_t)(v & 0xffffu);
      o[p * 2 + 1] = (ushort_t)(v >> 16);
    }
    *(u16x8*)(dst + j * 8) = o;
  }
}

// ---------------- ktransY: Ycb[4096 m][2048 c] -> YcT[2048 c][4096 m] (bf16) ----------------
__global__ void ktransY(const ushort_t* __restrict__ Y, ushort_t* __restrict__ YT) {
  int mt = blockIdx.x;  // 0..63
  int ct = blockIdx.y;  // 0..31
  __shared__ ushort_t tile[64][80];  // 16B-aligned rows
  int t = threadIdx.x;
  int r = t >> 2, cseg = (t & 3) * 16;
  const ushort_t* src = Y + (size_t)(mt * 64 + r) * 2048 + ct * 64 + cseg;
  *(u16x8*)&tile[r][cseg] = *(const u16x8*)src;
  *(u16x8*)&tile[r][cseg + 8] = *(const u16x8*)(src + 8);
  __syncthreads();
  int cl = t >> 2, mseg = (t & 3) * 16;
  u16x8 o0, o1;
#pragma unroll
  for (int j = 0; j < 8; ++j) o0[j] = tile[mseg + j][cl];
#pragma unroll
  for (int j = 0; j < 8; ++j) o1[j] = tile[mseg + 8 + j][cl];
  ushort_t* dst = YT + (size_t)(ct * 64 + cl) * 4096 + mt * 64 + mseg;
  *(u16x8*)dst = o0;
  *(u16x8*)(dst + 8) = o1;
}

// ---------------- K6: VLAD einsum via MFMA ----------------
// out[b,k,d] = sum_g sum_m wT[b, g*128+k, m] * YcT[g*256+d, b*512+m]
// grid (8: kt*4+dt? -> x: kt=x>>2, dt=x&3, y: m-split 2, z: b). 64x64 tile, BK=32.
__launch_bounds__(256)
__global__ void k6_vlad_mfma(const ushort_t* __restrict__ wT, const ushort_t* __restrict__ YcT,
                             float* __restrict__ vpart) {
  int kt = blockIdx.x >> 2, dt = blockIdx.x & 3;
  int ms = blockIdx.y, b = blockIdx.z;
  __shared__ alignas(16) ushort_t Ash[64 * 32];
  __shared__ alignas(16) ushort_t Bsh[64 * 32];
  int tid = threadIdx.x;
  int w = tid >> 6, l = tid & 63;
  int wr = w >> 1, wc = w & 1;
  int srow = tid >> 2, sk = (tid & 3) * 8;
  const ushort_t* Ag = wT + ((size_t)b * 1024 + kt * 64 + srow) * 512 + ms * 256 + sk;
  const ushort_t* Bg = YcT + (size_t)(dt * 64 + srow) * 4096 + b * 512 + ms * 256 + sk;
  ushort_t* ldsA = Ash + w * 512;
  ushort_t* ldsB = Bsh + w * 512;

  f32x4 acc[2][2];
#pragma unroll
  for (int i = 0; i < 2; ++i)
#pragma unroll
    for (int j = 0; j < 2; ++j) acc[i][j] = (f32x4){0.f, 0.f, 0.f, 0.f};

  for (int it = 0; it < 64; ++it) {
    int g = it >> 3, m0 = (it & 7) * 32;
    gload_lds16(Ag + (size_t)g * 65536 + m0, ldsA);
    gload_lds16(Bg + (size_t)g * 1048576 + m0, ldsB);
    __syncthreads();
    s16x8 af[2], bf2[2];
#pragma unroll
    for (int mi = 0; mi < 2; ++mi) {
      af[mi]  = *(const s16x8*)(Ash + (wr * 32 + mi * 16 + (l & 15)) * 32 + (l >> 4) * 8);
      bf2[mi] = *(const s16x8*)(Bsh + (wc * 32 + mi * 16 + (l & 15)) * 32 + (l >> 4) * 8);
    }
#pragma unroll
    for (int mi = 0; mi < 2; ++mi)
#pragma unroll
      for (int ni = 0; ni < 2; ++ni)
        acc[mi][ni] = __builtin_amdgcn_mfma_f32_16x16x32_bf16(af[mi], bf2[ni], acc[mi][ni], 0, 0, 0);
    __syncthreads();
  }

#pragma unroll
  for (int mi = 0; mi < 2; ++mi) {
    int row = kt * 64 + wr * 32 + mi * 16 + (l >> 4) * 4;
#pragma unroll
    for (int ni = 0; ni < 2; ++ni) {
      int col = dt * 64 + wc * 32 + ni * 16 + (l & 15);
#pragma unroll
      for (int r = 0; r < 4; ++r)
        vpart[((size_t)(ms * 8 + b) * 128 + row + r) * 256 + col] = acc[mi][ni][r];
    }
  }
}

// ---------------- K7: combine partials + bias-part - S*centroid, intra-normalize ----------------
__global__ void k7_intranorm(const float* __restrict__ vpart, const float* __restrict__ colsumW,
                             const float* __restrict__ b_inp, const float* __restrict__ cent,
                             float* __restrict__ out, float* __restrict__ ss1) {
  int k = blockIdx.x;
  int b = blockIdx.y;
  int d = threadIdx.x;
  float S = 0.f, bp = 0.f;
#pragma unroll
  for (int g = 0; g < 8; ++g) {
    float cw = colsumW[b * 1024 + g * 128 + k];
    S += cw;
    bp = fmaf(b_inp[g * 256 + d], cw, bp);
  }
  size_t off = ((size_t)b * 128 + k) * 256 + d;
  float v = vpart[off] + vpart[off + 262144] + bp - S * cent[(size_t)k * 256 + d];
  float ss = v * v;
#pragma unroll
  for (int m = 1; m < 64; m <<= 1) ss += __shfl_xor(ss, m, 64);
  __shared__ float red[4];
  int lane = d & 63, wv = d >> 6;
  if (lane == 0) red[wv] = ss;
  __syncthreads();
  float tot = red[0] + red[1] + red[2] + red[3];
  float rinv = 1.0f / fmaxf(sqrtf(tot), EPSN);
  out[off] = v * rinv;
  if (d == 0) ss1[b * 128 + k] = tot * rinv * rinv;
}

// ---------------- K8: final global L2 norm ----------------
__global__ void k8_finalnorm(const float* __restrict__ ss1, float* __restrict__ out) {
  int b = blockIdx.x;
  int t = threadIdx.x;
  __shared__ float red[256];
  red[t] = (t < 128) ? ss1[b * 128 + t] : 0.f;
  __syncthreads();
  for (int o = 128; o > 0; o >>= 1) {
    if (t < o) red[t] += red[t + o];
    __syncthreads();
  }
  float rinv = 1.0f / fmaxf(sqrtf(red[0]), EPSN);
  float* op = out + (size_t)b * 32768;
  for (int i = t; i < 32768; i += 256) op[i] *= rinv;
}

extern "C" void kernel_launch(void* const* d_in, const int* in_sizes, int n_in,
                              void* d_out, int out_size, void* d_ws, size_t ws_size,
                              hipStream_t stream) {
  const float* x     = (const float*)d_in[0];
  const float* W_inp = (const float*)d_in[1];
  const float* b_inp = (const float*)d_in[2];
  const float* W_g   = (const float*)d_in[3];
  const float* b_g   = (const float*)d_in[4];
  const float* W_gk  = (const float*)d_in[5];
  // b_gk (d_in[6]) cancels in the token-axis softmax — unused.
  const float* cent  = (const float*)d_in[7];
  float* out = (float*)d_out;
  float* ws = (float*)d_ws;

  // workspace layout (float offsets), total ~52.6 MB
  float* ssq     = ws + 0;        // 4096
  float* colsumW = ws + 4096;     // 8192
  float* ss1     = ws + 12288;    // 1024
  float* ag      = ws + 13312;    // 32768 (ends 46080)
  float* bWg     = ws + 46080;    // 64
  float* vpart   = ws + 46144;    // 524288 (ends 570432)
  float* logits  = ws + 570432;   // 4194304 (ends 4764736); YcT aliases after k5
  ushort_t* YcT  = (ushort_t*)logits;
  __hip_bfloat16* xnb = (__hip_bfloat16*)(ws + 4764736);  // 2097152 floats
  ushort_t* wT   = (ushort_t*)xnb;                        // alias (xnb dead after GEMM1)
  __hip_bfloat16* Wib  = (__hip_bfloat16*)(ws + 6861888); // 1048576
  __hip_bfloat16* Wgkb = (__hip_bfloat16*)(ws + 7910464); // 1048576
  __hip_bfloat16* Ycb  = (__hip_bfloat16*)(ws + 8959040); // 4194304 (ends 13153344)

  hipMemsetAsync(ssq, 0, 4096 * sizeof(float), stream);
  k0_ssq<<<512, 256, 0, stream>>>(x, ssq);
  k1_transpose<<<dim3(16, 64), 256, 0, stream>>>(x, ssq, xnb);
  kpack<<<2048, 256, 0, stream>>>(W_inp, Wib, 2097152);
  kpack<<<2048, 256, 0, stream>>>(W_gk, Wgkb, 2097152);
  kbw<<<8, 256, 0, stream>>>(W_g, b_inp, b_g, bWg);
  // GEMM1: Ycb[4096,2048] = xnb @ Wib^T  (centered: bias folded out)
  gemm_bf16_nt<0><<<dim3(16, 32), 256, 0, stream>>>(xnb, Wib, Ycb, nullptr, 1024, 2048);
  k3_alpha_g<<<256, 256, 0, stream>>>(Ycb, W_g, bWg, ag);
  // GEMM2: logits[4096,1024] = Ycb @ Wgkb^T  (column-constant bias cancels in softmax)
  gemm_bf16_nt<1><<<dim3(8, 32), 256, 0, stream>>>(Ycb, Wgkb, nullptr, logits, 2048, 1024);
  k5_softmax<<<dim3(16, 8), 512, 0, stream>>>(logits, ag, colsumW, wT);
  ktransY<<<dim3(64, 32), 256, 0, stream>>>((const ushort_t*)Ycb, YcT);  // logits dead now
  k6_vlad_mfma<<<dim3(8, 2, 8), 256, 0, stream>>>(wT, YcT, vpart);
  k7_intranorm<<<dim3(128, 8), 256, 0, stream>>>(vpart, colsumW, b_inp, cent, out, ss1);
  k8_finalnorm<<<8, 256, 0, stream>>>(ss1, out);
}

// Round 4
// 193.361 us; speedup vs baseline: 3.5240x; 1.1588x over previous
//
#include <hip/hip_runtime.h>
#include <hip/hip_bf16.h>
#include <math.h>

#define EPSN 1e-12f
typedef unsigned short ushort_t;

typedef float f32x4 __attribute__((ext_vector_type(4)));
typedef short s16x8 __attribute__((ext_vector_type(8)));
typedef unsigned short u16x8 __attribute__((ext_vector_type(8)));

__device__ __forceinline__ void gload_lds16(const void* g, void* l) {
  __builtin_amdgcn_global_load_lds((const __attribute__((address_space(1))) void*)g,
                                   (__attribute__((address_space(3))) void*)l, 16, 0, 0);
}

// ---------------- K0: per-token sum of squares (atomic partials) ----------------
__global__ void k0_ssq(const float* __restrict__ x, float* __restrict__ ssq) {
  int b8 = blockIdx.x >> 3;
  int cc = blockIdx.x & 7;
  int t = threadIdx.x;
  int s4 = (t & 15) * 4;
  int cg = t >> 4;
  const float* xp = x + (size_t)b8 * 65536 + (size_t)cc * 128 * 64;
  float4 a = {0.f, 0.f, 0.f, 0.f};
#pragma unroll
  for (int j = 0; j < 8; ++j) {
    int c = cg + j * 16;
    float4 v = *(const float4*)(xp + (size_t)c * 64 + s4);
    a.x = fmaf(v.x, v.x, a.x);
    a.y = fmaf(v.y, v.y, a.y);
    a.z = fmaf(v.z, v.z, a.z);
    a.w = fmaf(v.w, v.w, a.w);
  }
  __shared__ float red[16][68];
  *(float4*)&red[cg][s4] = a;
  __syncthreads();
  if (t < 64) {
    float s = 0.f;
#pragma unroll
    for (int g = 0; g < 16; ++g) s += red[g][t];
    atomicAdd(&ssq[b8 * 64 + t], s);
  }
}

// ---------------- K1: transpose + scale -> xnb bf16 [tm][c] ----------------
__global__ void k1_transpose(const float* __restrict__ x, const float* __restrict__ ssq,
                             __hip_bfloat16* __restrict__ xnb) {
  int ct = blockIdx.x;
  int b8 = blockIdx.y;
  int t = threadIdx.x;
  __shared__ float tile[64][65];
  int s = t & 63, cq = t >> 6;
  const float* xp = x + (size_t)b8 * 65536 + (size_t)ct * 64 * 64;
#pragma unroll
  for (int r = 0; r < 16; ++r) {
    int cl = cq * 16 + r;
    tile[cl][s] = xp[cl * 64 + s];
  }
  __syncthreads();
  int cl = t & 63, sq = t >> 6;
#pragma unroll
  for (int r = 0; r < 16; ++r) {
    int smm = sq * 16 + r;
    int tm = b8 * 64 + smm;
    float iv = rsqrtf(fmaxf(ssq[tm], 1e-24f));
    xnb[(size_t)tm * 1024 + ct * 64 + cl] = __float2bfloat16(tile[cl][smm] * iv);
  }
}

// ---------------- pack fp32 -> bf16 ----------------
__global__ void kpack(const float* __restrict__ in, __hip_bfloat16* __restrict__ out, int n) {
  int i = (blockIdx.x * 256 + threadIdx.x) * 4;
  if (i < n) {
    float4 v = *(const float4*)(in + i);
    out[i + 0] = __float2bfloat16(v.x);
    out[i + 1] = __float2bfloat16(v.y);
    out[i + 2] = __float2bfloat16(v.z);
    out[i + 3] = __float2bfloat16(v.w);
  }
}

// ---------------- bWg[j] = b_inp @ W_g[j,:] + b_g[j] ----------------
__global__ void kbw(const float* __restrict__ W_g, const float* __restrict__ b_inp,
                    const float* __restrict__ b_g, float* __restrict__ bWg) {
  int j = blockIdx.x;
  const float* row = W_g + (size_t)j * 2048;
  int t = threadIdx.x;
  float s = 0.f;
  for (int c = t; c < 2048; c += 256) s = fmaf(b_inp[c], row[c], s);
  __shared__ float red[256];
  red[t] = s;
  __syncthreads();
  for (int o = 128; o > 0; o >>= 1) {
    if (t < o) red[t] += red[t + o];
    __syncthreads();
  }
  if (t == 0) bWg[j] = red[0] + b_g[j];
}

// ---------------- bf16 MFMA NT GEMM, BK=64, double-buffered, 1 barrier/step ----------------
// C[M,N] = A[M,K] @ B[N,K]^T. 128x128 tile, 256 threads (4 waves 2x2).
// OUT: 0 = bf16, 1 = f32
template <int OUT>
__launch_bounds__(256)
__global__ void gemm_bf16_nt_db(const ushort_t* __restrict__ A, const ushort_t* __restrict__ B,
                                ushort_t* __restrict__ Cb, float* __restrict__ Cf,
                                int K, int N) {
  __shared__ alignas(16) ushort_t Ash[2][8192];
  __shared__ alignas(16) ushort_t Bsh[2][8192];
  const int tid = threadIdx.x;
  const int m0 = blockIdx.y * 128, n0 = blockIdx.x * 128;
  const int w = tid >> 6, l = tid & 63;
  const int wr = w >> 1, wc = w & 1;
  const int crow = l >> 3;       // 0..7 within chunk
  const int ck8 = (l & 7) * 8;   // k element offset

  const ushort_t* Ap[4];
  const ushort_t* Bp[4];
  int loff[4];
#pragma unroll
  for (int c = 0; c < 4; ++c) {
    int chunk = w * 4 + c;  // 0..15, 8 rows each
    Ap[c] = A + (size_t)(m0 + chunk * 8 + crow) * K + ck8;
    Bp[c] = B + (size_t)(n0 + chunk * 8 + crow) * K + ck8;
    loff[c] = chunk * 512;
  }

  f32x4 acc[4][4];
#pragma unroll
  for (int i = 0; i < 4; ++i)
#pragma unroll
    for (int j = 0; j < 4; ++j) acc[i][j] = (f32x4){0.f, 0.f, 0.f, 0.f};

#define STAGE(buf, k0)                                     \
  {                                                        \
    _Pragma("unroll") for (int c = 0; c < 4; ++c)          \
        gload_lds16(Ap[c] + (k0), &Ash[buf][loff[c]]);     \
    _Pragma("unroll") for (int c = 0; c < 4; ++c)          \
        gload_lds16(Bp[c] + (k0), &Bsh[buf][loff[c]]);     \
  }

#define COMPUTE(buf)                                                                     \
  {                                                                                      \
    s16x8 af[4][2], bf[4][2];                                                            \
    _Pragma("unroll") for (int mi = 0; mi < 4; ++mi) {                                   \
      _Pragma("unroll") for (int kk = 0; kk < 2; ++kk) {                                 \
        af[mi][kk] = *(const s16x8*)&Ash[buf][(wr * 64 + mi * 16 + (l & 15)) * 64 +      \
                                             kk * 32 + (l >> 4) * 8];                    \
        bf[mi][kk] = *(const s16x8*)&Bsh[buf][(wc * 64 + mi * 16 + (l & 15)) * 64 +      \
                                             kk * 32 + (l >> 4) * 8];                    \
      }                                                                                  \
    }                                                                                    \
    _Pragma("unroll") for (int kk = 0; kk < 2; ++kk)                                     \
        _Pragma("unroll") for (int mi = 0; mi < 4; ++mi)                                 \
            _Pragma("unroll") for (int ni = 0; ni < 4; ++ni)                             \
                acc[mi][ni] = __builtin_amdgcn_mfma_f32_16x16x32_bf16(af[mi][kk],        \
                                                                     bf[ni][kk],        \
                                                                     acc[mi][ni], 0, 0, 0); \
  }

  const int nt = K >> 6;
  STAGE(0, 0);
  __syncthreads();
  int buf = 0;
  for (int t = 0; t < nt - 1; ++t) {
    STAGE(buf ^ 1, (t + 1) << 6);
    COMPUTE(buf);
    __syncthreads();
    buf ^= 1;
  }
  COMPUTE(buf);
#undef STAGE
#undef COMPUTE

#pragma unroll
  for (int mi = 0; mi < 4; ++mi) {
    int row = m0 + wr * 64 + mi * 16 + (l >> 4) * 4;
#pragma unroll
    for (int ni = 0; ni < 4; ++ni) {
      int col = n0 + wc * 64 + ni * 16 + (l & 15);
#pragma unroll
      for (int r = 0; r < 4; ++r) {
        if constexpr (OUT == 0) {
          __hip_bfloat16 hb = __float2bfloat16(acc[mi][ni][r]);
          Cb[(size_t)(row + r) * N + col] = *(ushort_t*)&hb;
        } else {
          Cf[(size_t)(row + r) * N + col] = acc[mi][ni][r];
        }
      }
    }
  }
}

// ---------------- K3: agT[g][tm] = sigmoid(Yc @ W_g^T + bWg) ----------------
__global__ void k3_alpha_g(const __hip_bfloat16* __restrict__ Yc, const float* __restrict__ Wg,
                           const float* __restrict__ bWg, float* __restrict__ agT) {
  __shared__ float wgs[8 * 2048];
  int t = threadIdx.x;
  for (int r = 0; r < 64; ++r) wgs[t + r * 256] = Wg[t + r * 256];
  __syncthreads();
  int team = t >> 4, i = t & 15;
  int tok = blockIdx.x * 16 + team;
  const __hip_bfloat16* yp = Yc + (size_t)tok * 2048;
  float acc[8] = {0, 0, 0, 0, 0, 0, 0, 0};
  for (int c0 = i * 8; c0 < 2048; c0 += 128) {
    u16x8 y8 = *(const u16x8*)(yp + c0);
#pragma unroll
    for (int j = 0; j < 8; ++j) {
      float yf = __uint_as_float(((unsigned)y8[j]) << 16);
#pragma unroll
      for (int g = 0; g < 8; ++g)
        acc[g] = fmaf(yf, wgs[g * 2048 + c0 + j], acc[g]);
    }
  }
#pragma unroll
  for (int g = 0; g < 8; ++g) {
    acc[g] += __shfl_xor(acc[g], 1, 16);
    acc[g] += __shfl_xor(acc[g], 2, 16);
    acc[g] += __shfl_xor(acc[g], 4, 16);
    acc[g] += __shfl_xor(acc[g], 8, 16);
  }
  if (i < 8) {
    float v = 0.f;
#pragma unroll
    for (int g = 0; g < 8; ++g)
      if (g == i) v = acc[g];
    v += bWg[i];
    agT[(size_t)i * 4096 + tok] = 1.0f / (1.0f + expf(-v));
  }
}

// ---------------- K5: row softmax over tokens, one wave per (q,b) ----------------
// logitsT[1024 q][4096 tm] -> wbT bf16 [q][tm], colsumW[b*1024+q]
__launch_bounds__(256)
__global__ void k5_softmax(const float* __restrict__ logitsT, const float* __restrict__ agT,
                           float* __restrict__ colsumW, ushort_t* __restrict__ wbT) {
  int wv = (blockIdx.x << 2) + (threadIdx.x >> 6);
  int q = wv >> 3, b = wv & 7;
  int l = threadIdx.x & 63;
  int g = q >> 7;
  size_t base = (size_t)q * 4096 + b * 512 + l * 8;
  float4 v0 = *(const float4*)(logitsT + base);
  float4 v1 = *(const float4*)(logitsT + base + 4);
  float vs[8] = {v0.x, v0.y, v0.z, v0.w, v1.x, v1.y, v1.z, v1.w};
  float M = vs[0];
#pragma unroll
  for (int i = 1; i < 8; ++i) M = fmaxf(M, vs[i]);
#pragma unroll
  for (int m = 1; m < 64; m <<= 1) M = fmaxf(M, __shfl_xor(M, m, 64));
  float e[8], S = 0.f;
#pragma unroll
  for (int i = 0; i < 8; ++i) {
    e[i] = expf(vs[i] - M);
    S += e[i];
  }
#pragma unroll
  for (int m = 1; m < 64; m <<= 1) S += __shfl_xor(S, m, 64);
  float R = 1.0f / S;
  size_t abase = (size_t)g * 4096 + b * 512 + l * 8;
  float4 a0 = *(const float4*)(agT + abase);
  float4 a1 = *(const float4*)(agT + abase + 4);
  float ag[8] = {a0.x, a0.y, a0.z, a0.w, a1.x, a1.y, a1.z, a1.w};
  float wv8[8], wsum = 0.f;
#pragma unroll
  for (int i = 0; i < 8; ++i) {
    wv8[i] = e[i] * R * ag[i];
    wsum += wv8[i];
  }
#pragma unroll
  for (int m = 1; m < 64; m <<= 1) wsum += __shfl_xor(wsum, m, 64);
  if (l == 0) colsumW[b * 1024 + q] = wsum;
  u16x8 o;
#pragma unroll
  for (int i = 0; i < 8; ++i) {
    __hip_bfloat16 hb = __float2bfloat16(wv8[i]);
    o[i] = *(ushort_t*)&hb;
  }
  *(u16x8*)(wbT + base) = o;
}

// ---------------- ktransY: Ycb[4096 m][2048 c] -> YcT[2048 c][4096 m] ----------------
__global__ void ktransY(const ushort_t* __restrict__ Y, ushort_t* __restrict__ YT) {
  int mt = blockIdx.x;
  int ct = blockIdx.y;
  __shared__ ushort_t tile[64][80];
  int t = threadIdx.x;
  int r = t >> 2, cseg = (t & 3) * 16;
  const ushort_t* src = Y + (size_t)(mt * 64 + r) * 2048 + ct * 64 + cseg;
  *(u16x8*)&tile[r][cseg] = *(const u16x8*)src;
  *(u16x8*)&tile[r][cseg + 8] = *(const u16x8*)(src + 8);
  __syncthreads();
  int cl = t >> 2, mseg = (t & 3) * 16;
  u16x8 o0, o1;
#pragma unroll
  for (int j = 0; j < 8; ++j) o0[j] = tile[mseg + j][cl];
#pragma unroll
  for (int j = 0; j < 8; ++j) o1[j] = tile[mseg + 8 + j][cl];
  ushort_t* dst = YT + (size_t)(ct * 64 + cl) * 4096 + mt * 64 + mseg;
  *(u16x8*)dst = o0;
  *(u16x8*)(dst + 8) = o1;
}

// ---------------- K6: VLAD einsum via MFMA, 64x64 tile, BK=64, dbuf ----------------
// out[b,k,d] = sum_{g,m} wbT[g*128+k][b*512+m] * YcT[g*256+d][b*512+m]
__launch_bounds__(256)
__global__ void k6_vlad_mfma(const ushort_t* __restrict__ wbT, const ushort_t* __restrict__ YcT,
                             float* __restrict__ vpart) {
  int kt = blockIdx.x >> 2, dt = blockIdx.x & 3;
  int ms = blockIdx.y, b = blockIdx.z;
  __shared__ alignas(16) ushort_t Ash[2][4096];
  __shared__ alignas(16) ushort_t Bsh[2][4096];
  const int tid = threadIdx.x;
  const int w = tid >> 6, l = tid & 63;
  const int wr = w >> 1, wc = w & 1;
  const int crow = l >> 3;
  const int ck8 = (l & 7) * 8;

  const ushort_t* Ap[2];
  const ushort_t* Bp[2];
  int loff[2];
#pragma unroll
  for (int c = 0; c < 2; ++c) {
    int chunk = w * 2 + c;  // 0..7
    Ap[c] = wbT + (size_t)(kt * 64 + chunk * 8 + crow) * 4096 + b * 512 + ms * 256 + ck8;
    Bp[c] = YcT + (size_t)(dt * 64 + chunk * 8 + crow) * 4096 + b * 512 + ms * 256 + ck8;
    loff[c] = chunk * 512;
  }

  f32x4 acc[2][2];
#pragma unroll
  for (int i = 0; i < 2; ++i)
#pragma unroll
    for (int j = 0; j < 2; ++j) acc[i][j] = (f32x4){0.f, 0.f, 0.f, 0.f};

#define STAGE6(buf, s)                                                       \
  {                                                                          \
    size_t offA = (size_t)((s) >> 2) * 524288 + ((s)&3) * 64;                \
    size_t offB = (size_t)((s) >> 2) * 1048576 + ((s)&3) * 64;               \
    _Pragma("unroll") for (int c = 0; c < 2; ++c)                            \
        gload_lds16(Ap[c] + offA, &Ash[buf][loff[c]]);                       \
    _Pragma("unroll") for (int c = 0; c < 2; ++c)                            \
        gload_lds16(Bp[c] + offB, &Bsh[buf][loff[c]]);                       \
  }

#define COMPUTE6(buf)                                                                    \
  {                                                                                      \
    s16x8 af[2][2], bf[2][2];                                                            \
    _Pragma("unroll") for (int mi = 0; mi < 2; ++mi) {                                   \
      _Pragma("unroll") for (int kk = 0; kk < 2; ++kk) {                                 \
        af[mi][kk] = *(const s16x8*)&Ash[buf][(wr * 32 + mi * 16 + (l & 15)) * 64 +      \
                                             kk * 32 + (l >> 4) * 8];                    \
        bf[mi][kk] = *(const s16x8*)&Bsh[buf][(wc * 32 + mi * 16 + (l & 15)) * 64 +      \
                                             kk * 32 + (l >> 4) * 8];                    \
      }                                                                                  \
    }                                                                                    \
    _Pragma("unroll") for (int kk = 0; kk < 2; ++kk)                                     \
        _Pragma("unroll") for (int mi = 0; mi < 2; ++mi)                                 \
            _Pragma("unroll") for (int ni = 0; ni < 2; ++ni)                             \
                acc[mi][ni] = __builtin_amdgcn_mfma_f32_16x16x32_bf16(af[mi][kk],        \
                                                                     bf[ni][kk],        \
                                                                     acc[mi][ni], 0, 0, 0); \
  }

  STAGE6(0, 0);
  __syncthreads();
  int buf = 0;
  for (int s = 0; s < 31; ++s) {
    STAGE6(buf ^ 1, s + 1);
    COMPUTE6(buf);
    __syncthreads();
    buf ^= 1;
  }
  COMPUTE6(buf);
#undef STAGE6
#undef COMPUTE6

#pragma unroll
  for (int mi = 0; mi < 2; ++mi) {
    int row = kt * 64 + wr * 32 + mi * 16 + (l >> 4) * 4;
#pragma unroll
    for (int ni = 0; ni < 2; ++ni) {
      int col = dt * 64 + wc * 32 + ni * 16 + (l & 15);
#pragma unroll
      for (int r = 0; r < 4; ++r)
        vpart[((size_t)(ms * 8 + b) * 128 + row + r) * 256 + col] = acc[mi][ni][r];
    }
  }
}

// ---------------- K7: combine partials + bias-part - S*centroid, intra-normalize ----------------
__global__ void k7_intranorm(const float* __restrict__ vpart, const float* __restrict__ colsumW,
                             const float* __restrict__ b_inp, const float* __restrict__ cent,
                             float* __restrict__ out, float* __restrict__ ss1) {
  int k = blockIdx.x;
  int b = blockIdx.y;
  int d = threadIdx.x;
  float S = 0.f, bp = 0.f;
#pragma unroll
  for (int g = 0; g < 8; ++g) {
    float cw = colsumW[b * 1024 + g * 128 + k];
    S += cw;
    bp = fmaf(b_inp[g * 256 + d], cw, bp);
  }
  size_t off = ((size_t)b * 128 + k) * 256 + d;
  float v = vpart[off] + vpart[off + 262144] + bp - S * cent[(size_t)k * 256 + d];
  float ss = v * v;
#pragma unroll
  for (int m = 1; m < 64; m <<= 1) ss += __shfl_xor(ss, m, 64);
  __shared__ float red[4];
  int lane = d & 63, wv = d >> 6;
  if (lane == 0) red[wv] = ss;
  __syncthreads();
  float tot = red[0] + red[1] + red[2] + red[3];
  float rinv = 1.0f / fmaxf(sqrtf(tot), EPSN);
  out[off] = v * rinv;
  if (d == 0) ss1[b * 128 + k] = tot * rinv * rinv;
}

// ---------------- K8: final global L2 norm ----------------
__global__ void k8_finalnorm(const float* __restrict__ ss1, float* __restrict__ out) {
  int b = blockIdx.x;
  int t = threadIdx.x;
  __shared__ float red[256];
  red[t] = (t < 128) ? ss1[b * 128 + t] : 0.f;
  __syncthreads();
  for (int o = 128; o > 0; o >>= 1) {
    if (t < o) red[t] += red[t + o];
    __syncthreads();
  }
  float rinv = 1.0f / fmaxf(sqrtf(red[0]), EPSN);
  float* op = out + (size_t)b * 32768;
  for (int i = t; i < 32768; i += 256) op[i] *= rinv;
}

extern "C" void kernel_launch(void* const* d_in, const int* in_sizes, int n_in,
                              void* d_out, int out_size, void* d_ws, size_t ws_size,
                              hipStream_t stream) {
  const float* x     = (const float*)d_in[0];
  const float* W_inp = (const float*)d_in[1];
  const float* b_inp = (const float*)d_in[2];
  const float* W_g   = (const float*)d_in[3];
  const float* b_g   = (const float*)d_in[4];
  const float* W_gk  = (const float*)d_in[5];
  // b_gk (d_in[6]) cancels in the token-axis softmax — unused.
  const float* cent  = (const float*)d_in[7];
  float* out = (float*)d_out;
  float* ws = (float*)d_ws;

  // workspace layout (float offsets), total ~52.6 MB
  float* ssq     = ws + 0;        // 4096
  float* colsumW = ws + 4096;     // 8192
  float* ss1     = ws + 12288;    // 1024
  float* agT     = ws + 13312;    // 32768 [8 g][4096 tm] (ends 46080)
  float* bWg     = ws + 46080;    // 64
  float* vpart   = ws + 46144;    // 524288 (ends 570432)
  float* logitsT = ws + 570432;   // 4194304 [1024 q][4096 tm] (ends 4764736)
  ushort_t* YcT  = (ushort_t*)logitsT;                    // alias (logitsT dead after k5)
  __hip_bfloat16* xnb = (__hip_bfloat16*)(ws + 4764736);  // 2097152 floats
  ushort_t* wbT  = (ushort_t*)xnb;                        // alias (xnb dead after GEMM1)
  __hip_bfloat16* Wib  = (__hip_bfloat16*)(ws + 6861888); // 1048576
  __hip_bfloat16* Wgkb = (__hip_bfloat16*)(ws + 7910464); // 1048576
  __hip_bfloat16* Ycb  = (__hip_bfloat16*)(ws + 8959040); // 4194304 (ends 13153344)

  hipMemsetAsync(ssq, 0, 4096 * sizeof(float), stream);
  k0_ssq<<<512, 256, 0, stream>>>(x, ssq);
  k1_transpose<<<dim3(16, 64), 256, 0, stream>>>(x, ssq, xnb);
  kpack<<<2048, 256, 0, stream>>>(W_inp, Wib, 2097152);
  kpack<<<2048, 256, 0, stream>>>(W_gk, Wgkb, 2097152);
  kbw<<<8, 256, 0, stream>>>(W_g, b_inp, b_g, bWg);
  // GEMM1: Ycb[4096,2048] = xnb @ Wib^T  (centered: bias folded out)
  gemm_bf16_nt_db<0><<<dim3(16, 32), 256, 0, stream>>>((const ushort_t*)xnb, (const ushort_t*)Wib,
                                                       (ushort_t*)Ycb, nullptr, 1024, 2048);
  k3_alpha_g<<<256, 256, 0, stream>>>(Ycb, W_g, bWg, agT);
  // GEMM2 (transposed): logitsT[1024,4096] = Wgkb @ Ycb^T
  gemm_bf16_nt_db<1><<<dim3(32, 8), 256, 0, stream>>>((const ushort_t*)Wgkb, (const ushort_t*)Ycb,
                                                      nullptr, logitsT, 2048, 4096);
  k5_softmax<<<2048, 256, 0, stream>>>(logitsT, agT, colsumW, wbT);
  ktransY<<<dim3(64, 32), 256, 0, stream>>>((const ushort_t*)Ycb, YcT);  // logitsT dead now
  k6_vlad_mfma<<<dim3(8, 2, 8), 256, 0, stream>>>(wbT, YcT, vpart);
  k7_intranorm<<<dim3(128, 8), 256, 0, stream>>>(vpart, colsumW, b_inp, cent, out, ss1);
  k8_finalnorm<<<8, 256, 0, stream>>>(ss1, out);
}

// Round 5
// 172.661 us; speedup vs baseline: 3.9465x; 1.1199x over previous
//
#include <hip/hip_runtime.h>
#include <hip/hip_bf16.h>
#include <math.h>

#define EPSN 1e-12f
typedef unsigned short ushort_t;

typedef float f32x4 __attribute__((ext_vector_type(4)));
typedef short s16x8 __attribute__((ext_vector_type(8)));
typedef unsigned short u16x8 __attribute__((ext_vector_type(8)));

__device__ __forceinline__ void gload_lds16(const void* g, void* l) {
  __builtin_amdgcn_global_load_lds((const __attribute__((address_space(1))) void*)g,
                                   (__attribute__((address_space(3))) void*)l, 16, 0, 0);
}

// ---------------- K0: per-token sum of squares -> 8 partials (no atomics) ----------------
__global__ void k0_ssq(const float* __restrict__ x, float* __restrict__ ssq8) {
  int b8 = blockIdx.x >> 3;
  int cc = blockIdx.x & 7;
  int t = threadIdx.x;
  int s4 = (t & 15) * 4;
  int cg = t >> 4;
  const float* xp = x + (size_t)b8 * 65536 + (size_t)cc * 128 * 64;
  float4 a = {0.f, 0.f, 0.f, 0.f};
#pragma unroll
  for (int j = 0; j < 8; ++j) {
    int c = cg + j * 16;
    float4 v = *(const float4*)(xp + (size_t)c * 64 + s4);
    a.x = fmaf(v.x, v.x, a.x);
    a.y = fmaf(v.y, v.y, a.y);
    a.z = fmaf(v.z, v.z, a.z);
    a.w = fmaf(v.w, v.w, a.w);
  }
  __shared__ float red[16][68];
  *(float4*)&red[cg][s4] = a;
  __syncthreads();
  if (t < 64) {
    float s = 0.f;
#pragma unroll
    for (int g = 0; g < 16; ++g) s += red[g][t];
    ssq8[cc * 4096 + b8 * 64 + t] = s;
  }
}

// ---------------- K1: transpose + scale -> xnb bf16 [tm][c] ----------------
__global__ void k1_transpose(const float* __restrict__ x, const float* __restrict__ ssq8,
                             __hip_bfloat16* __restrict__ xnb) {
  int ct = blockIdx.x;
  int b8 = blockIdx.y;
  int t = threadIdx.x;
  __shared__ float tile[64][65];
  __shared__ float ivs[64];
  if (t < 64) {
    float s = 0.f;
#pragma unroll
    for (int cc = 0; cc < 8; ++cc) s += ssq8[cc * 4096 + b8 * 64 + t];
    ivs[t] = rsqrtf(fmaxf(s, 1e-24f));
  }
  int s = t & 63, cq = t >> 6;
  const float* xp = x + (size_t)b8 * 65536 + (size_t)ct * 64 * 64;
#pragma unroll
  for (int r = 0; r < 16; ++r) {
    int cl = cq * 16 + r;
    tile[cl][s] = xp[cl * 64 + s];
  }
  __syncthreads();
  int cl = t & 63, sq = t >> 6;
#pragma unroll
  for (int r = 0; r < 16; ++r) {
    int smm = sq * 16 + r;
    int tm = b8 * 64 + smm;
    xnb[(size_t)tm * 1024 + ct * 64 + cl] = __float2bfloat16(tile[cl][smm] * ivs[smm]);
  }
}

// ---------------- pack fp32 -> bf16 (both weight matrices, one launch) ----------------
__global__ void kpack2(const float* __restrict__ a, const float* __restrict__ b,
                       __hip_bfloat16* __restrict__ oa, __hip_bfloat16* __restrict__ ob) {
  int bid = blockIdx.x;
  const float* in;
  __hip_bfloat16* out;
  int i;
  if (bid < 2048) {
    in = a; out = oa; i = (bid * 256 + threadIdx.x) * 4;
  } else {
    in = b; out = ob; i = ((bid - 2048) * 256 + threadIdx.x) * 4;
  }
  float4 v = *(const float4*)(in + i);
  out[i + 0] = __float2bfloat16(v.x);
  out[i + 1] = __float2bfloat16(v.y);
  out[i + 2] = __float2bfloat16(v.z);
  out[i + 3] = __float2bfloat16(v.w);
}

// ---------------- bWg[j] = b_inp @ W_g[j,:] + b_g[j] ----------------
__global__ void kbw(const float* __restrict__ W_g, const float* __restrict__ b_inp,
                    const float* __restrict__ b_g, float* __restrict__ bWg) {
  int j = blockIdx.x;
  const float* row = W_g + (size_t)j * 2048;
  int t = threadIdx.x;
  float s = 0.f;
  for (int c = t; c < 2048; c += 256) s = fmaf(b_inp[c], row[c], s);
  __shared__ float red[256];
  red[t] = s;
  __syncthreads();
  for (int o = 128; o > 0; o >>= 1) {
    if (t < o) red[t] += red[t + o];
    __syncthreads();
  }
  if (t == 0) bWg[j] = red[0] + b_g[j];
}

// ---------------- bf16 MFMA NT GEMM, BK=64, dbuf, XOR-swizzled LDS ----------------
// C[M,N] = A[M,K] @ B[N,K]^T. 128x128 tile, 256 threads (4 waves 2x2).
// LDS slot swizzle: physical 16B-slot p in row holds logical slot p ^ (row&7).
// Achieved by inverse-swizzling the per-lane GLOBAL source (linear LDS dest, rule #21).
// OUT: 0 = bf16, 1 = f32
template <int OUT>
__launch_bounds__(256)
__global__ void gemm_bf16_nt_db(const ushort_t* __restrict__ A, const ushort_t* __restrict__ B,
                                ushort_t* __restrict__ Cb, float* __restrict__ Cf,
                                int K, int N) {
  __shared__ alignas(16) ushort_t Ash[2][8192];
  __shared__ alignas(16) ushort_t Bsh[2][8192];
  const int tid = threadIdx.x;
  const int m0 = blockIdx.y * 128, n0 = blockIdx.x * 128;
  const int w = tid >> 6, l = tid & 63;
  const int wr = w >> 1, wc = w & 1;
  const int crow = l >> 3;                 // row within 8-row chunk; == row&7
  const int ksw = ((l & 7) ^ crow) * 8;    // inverse-swizzled source k-offset (elements)

  const ushort_t* Ap[4];
  const ushort_t* Bp[4];
  int loff[4];
#pragma unroll
  for (int c = 0; c < 4; ++c) {
    int chunk = w * 4 + c;  // 0..15, 8 rows each
    Ap[c] = A + (size_t)(m0 + chunk * 8 + crow) * K + ksw;
    Bp[c] = B + (size_t)(n0 + chunk * 8 + crow) * K + ksw;
    loff[c] = chunk * 512;
  }

  f32x4 acc[4][4];
#pragma unroll
  for (int i = 0; i < 4; ++i)
#pragma unroll
    for (int j = 0; j < 4; ++j) acc[i][j] = (f32x4){0.f, 0.f, 0.f, 0.f};

  const int sw = l & 7, qq = l >> 4;

#define STAGE(buf, k0)                                     \
  {                                                        \
    _Pragma("unroll") for (int c = 0; c < 4; ++c)          \
        gload_lds16(Ap[c] + (k0), &Ash[buf][loff[c]]);     \
    _Pragma("unroll") for (int c = 0; c < 4; ++c)          \
        gload_lds16(Bp[c] + (k0), &Bsh[buf][loff[c]]);     \
  }

#define COMPUTE(buf)                                                                     \
  {                                                                                      \
    s16x8 af[4][2], bf[4][2];                                                            \
    _Pragma("unroll") for (int mi = 0; mi < 4; ++mi) {                                   \
      _Pragma("unroll") for (int kk = 0; kk < 2; ++kk) {                                 \
        int slot = ((kk << 2) + qq) ^ sw;                                                \
        af[mi][kk] = *(const s16x8*)&Ash[buf][(wr * 64 + mi * 16 + (l & 15)) * 64 +      \
                                             slot * 8];                                  \
        bf[mi][kk] = *(const s16x8*)&Bsh[buf][(wc * 64 + mi * 16 + (l & 15)) * 64 +      \
                                             slot * 8];                                  \
      }                                                                                  \
    }                                                                                    \
    _Pragma("unroll") for (int kk = 0; kk < 2; ++kk)                                     \
        _Pragma("unroll") for (int mi = 0; mi < 4; ++mi)                                 \
            _Pragma("unroll") for (int ni = 0; ni < 4; ++ni)                             \
                acc[mi][ni] = __builtin_amdgcn_mfma_f32_16x16x32_bf16(af[mi][kk],        \
                                                                     bf[ni][kk],        \
                                                                     acc[mi][ni], 0, 0, 0); \
  }

  const int nt = K >> 6;
  STAGE(0, 0);
  __syncthreads();
  int buf = 0;
  for (int t = 0; t < nt - 1; ++t) {
    STAGE(buf ^ 1, (t + 1) << 6);
    COMPUTE(buf);
    __syncthreads();
    buf ^= 1;
  }
  COMPUTE(buf);
#undef STAGE
#undef COMPUTE

#pragma unroll
  for (int mi = 0; mi < 4; ++mi) {
    int row = m0 + wr * 64 + mi * 16 + (l >> 4) * 4;
#pragma unroll
    for (int ni = 0; ni < 4; ++ni) {
      int col = n0 + wc * 64 + ni * 16 + (l & 15);
#pragma unroll
      for (int r = 0; r < 4; ++r) {
        if constexpr (OUT == 0) {
          __hip_bfloat16 hb = __float2bfloat16(acc[mi][ni][r]);
          Cb[(size_t)(row + r) * N + col] = *(ushort_t*)&hb;
        } else {
          Cf[(size_t)(row + r) * N + col] = acc[mi][ni][r];
        }
      }
    }
  }
}

// ---------------- K3: agT[g][tm] = sigmoid(Yc @ W_g^T + bWg) ----------------
__global__ void k3_alpha_g(const __hip_bfloat16* __restrict__ Yc, const float* __restrict__ Wg,
                           const float* __restrict__ bWg, float* __restrict__ agT) {
  __shared__ float wgs[8 * 2048];
  int t = threadIdx.x;
  for (int r = 0; r < 64; ++r) wgs[t + r * 256] = Wg[t + r * 256];
  __syncthreads();
  int team = t >> 4, i = t & 15;
  int tok = blockIdx.x * 16 + team;
  const __hip_bfloat16* yp = Yc + (size_t)tok * 2048;
  float acc[8] = {0, 0, 0, 0, 0, 0, 0, 0};
  for (int c0 = i * 8; c0 < 2048; c0 += 128) {
    u16x8 y8 = *(const u16x8*)(yp + c0);
#pragma unroll
    for (int j = 0; j < 8; ++j) {
      float yf = __uint_as_float(((unsigned)y8[j]) << 16);
#pragma unroll
      for (int g = 0; g < 8; ++g)
        acc[g] = fmaf(yf, wgs[g * 2048 + c0 + j], acc[g]);
    }
  }
#pragma unroll
  for (int g = 0; g < 8; ++g) {
    acc[g] += __shfl_xor(acc[g], 1, 16);
    acc[g] += __shfl_xor(acc[g], 2, 16);
    acc[g] += __shfl_xor(acc[g], 4, 16);
    acc[g] += __shfl_xor(acc[g], 8, 16);
  }
  if (i < 8) {
    float v = 0.f;
#pragma unroll
    for (int g = 0; g < 8; ++g)
      if (g == i) v = acc[g];
    v += bWg[i];
    agT[(size_t)i * 4096 + tok] = 1.0f / (1.0f + expf(-v));
  }
}

// ---------------- K5: row softmax over tokens, one wave per (q,b) ----------------
__launch_bounds__(256)
__global__ void k5_softmax(const float* __restrict__ logitsT, const float* __restrict__ agT,
                           float* __restrict__ colsumW, ushort_t* __restrict__ wbT) {
  int wv = (blockIdx.x << 2) + (threadIdx.x >> 6);
  int q = wv >> 3, b = wv & 7;
  int l = threadIdx.x & 63;
  int g = q >> 7;
  size_t base = (size_t)q * 4096 + b * 512 + l * 8;
  float4 v0 = *(const float4*)(logitsT + base);
  float4 v1 = *(const float4*)(logitsT + base + 4);
  float vs[8] = {v0.x, v0.y, v0.z, v0.w, v1.x, v1.y, v1.z, v1.w};
  float M = vs[0];
#pragma unroll
  for (int i = 1; i < 8; ++i) M = fmaxf(M, vs[i]);
#pragma unroll
  for (int m = 1; m < 64; m <<= 1) M = fmaxf(M, __shfl_xor(M, m, 64));
  float e[8], S = 0.f;
#pragma unroll
  for (int i = 0; i < 8; ++i) {
    e[i] = expf(vs[i] - M);
    S += e[i];
  }
#pragma unroll
  for (int m = 1; m < 64; m <<= 1) S += __shfl_xor(S, m, 64);
  float R = 1.0f / S;
  size_t abase = (size_t)g * 4096 + b * 512 + l * 8;
  float4 a0 = *(const float4*)(agT + abase);
  float4 a1 = *(const float4*)(agT + abase + 4);
  float ag[8] = {a0.x, a0.y, a0.z, a0.w, a1.x, a1.y, a1.z, a1.w};
  float wv8[8], wsum = 0.f;
#pragma unroll
  for (int i = 0; i < 8; ++i) {
    wv8[i] = e[i] * R * ag[i];
    wsum += wv8[i];
  }
#pragma unroll
  for (int m = 1; m < 64; m <<= 1) wsum += __shfl_xor(wsum, m, 64);
  if (l == 0) colsumW[b * 1024 + q] = wsum;
  u16x8 o;
#pragma unroll
  for (int i = 0; i < 8; ++i) {
    __hip_bfloat16 hb = __float2bfloat16(wv8[i]);
    o[i] = *(ushort_t*)&hb;
  }
  *(u16x8*)(wbT + base) = o;
}

// ---------------- ktransY: Ycb[4096 m][2048 c] -> YcT[2048 c][4096 m] ----------------
__global__ void ktransY(const ushort_t* __restrict__ Y, ushort_t* __restrict__ YT) {
  int mt = blockIdx.x;
  int ct = blockIdx.y;
  __shared__ ushort_t tile[64][80];
  int t = threadIdx.x;
  int r = t >> 2, cseg = (t & 3) * 16;
  const ushort_t* src = Y + (size_t)(mt * 64 + r) * 2048 + ct * 64 + cseg;
  *(u16x8*)&tile[r][cseg] = *(const u16x8*)src;
  *(u16x8*)&tile[r][cseg + 8] = *(const u16x8*)(src + 8);
  __syncthreads();
  int cl = t >> 2, mseg = (t & 3) * 16;
  u16x8 o0, o1;
#pragma unroll
  for (int j = 0; j < 8; ++j) o0[j] = tile[mseg + j][cl];
#pragma unroll
  for (int j = 0; j < 8; ++j) o1[j] = tile[mseg + 8 + j][cl];
  ushort_t* dst = YT + (size_t)(ct * 64 + cl) * 4096 + mt * 64 + mseg;
  *(u16x8*)dst = o0;
  *(u16x8*)(dst + 8) = o1;
}

// ---------------- K6: VLAD einsum via MFMA, 64x64 tile, BK=64, dbuf, swizzled ----------------
__launch_bounds__(256)
__global__ void k6_vlad_mfma(const ushort_t* __restrict__ wbT, const ushort_t* __restrict__ YcT,
                             float* __restrict__ vpart) {
  int kt = blockIdx.x >> 2, dt = blockIdx.x & 3;
  int ms = blockIdx.y, b = blockIdx.z;
  __shared__ alignas(16) ushort_t Ash[2][4096];
  __shared__ alignas(16) ushort_t Bsh[2][4096];
  const int tid = threadIdx.x;
  const int w = tid >> 6, l = tid & 63;
  const int wr = w >> 1, wc = w & 1;
  const int crow = l >> 3;
  const int ksw = ((l & 7) ^ crow) * 8;

  const ushort_t* Ap[2];
  const ushort_t* Bp[2];
  int loff[2];
#pragma unroll
  for (int c = 0; c < 2; ++c) {
    int chunk = w * 2 + c;  // 0..7
    Ap[c] = wbT + (size_t)(kt * 64 + chunk * 8 + crow) * 4096 + b * 512 + ms * 256 + ksw;
    Bp[c] = YcT + (size_t)(dt * 64 + chunk * 8 + crow) * 4096 + b * 512 + ms * 256 + ksw;
    loff[c] = chunk * 512;
  }

  f32x4 acc[2][2];
#pragma unroll
  for (int i = 0; i < 2; ++i)
#pragma unroll
    for (int j = 0; j < 2; ++j) acc[i][j] = (f32x4){0.f, 0.f, 0.f, 0.f};

  const int sw = l & 7, qq = l >> 4;

#define STAGE6(buf, s)                                                       \
  {                                                                          \
    size_t offA = (size_t)((s) >> 2) * 524288 + ((s)&3) * 64;                \
    size_t offB = (size_t)((s) >> 2) * 1048576 + ((s)&3) * 64;               \
    _Pragma("unroll") for (int c = 0; c < 2; ++c)                            \
        gload_lds16(Ap[c] + offA, &Ash[buf][loff[c]]);                       \
    _Pragma("unroll") for (int c = 0; c < 2; ++c)                            \
        gload_lds16(Bp[c] + offB, &Bsh[buf][loff[c]]);                       \
  }

#define COMPUTE6(buf)                                                                    \
  {                                                                                      \
    s16x8 af[2][2], bf[2][2];                                                            \
    _Pragma("unroll") for (int mi = 0; mi < 2; ++mi) {                                   \
      _Pragma("unroll") for (int kk = 0; kk < 2; ++kk) {                                 \
        int slot = ((kk << 2) + qq) ^ sw;                                                \
        af[mi][kk] = *(const s16x8*)&Ash[buf][(wr * 32 + mi * 16 + (l & 15)) * 64 +      \
                                             slot * 8];                                  \
        bf[mi][kk] = *(const s16x8*)&Bsh[buf][(wc * 32 + mi * 16 + (l & 15)) * 64 +      \
                                             slot * 8];                                  \
      }                                                                                  \
    }                                                                                    \
    _Pragma("unroll") for (int kk = 0; kk < 2; ++kk)                                     \
        _Pragma("unroll") for (int mi = 0; mi < 2; ++mi)                                 \
            _Pragma("unroll") for (int ni = 0; ni < 2; ++ni)                             \
                acc[mi][ni] = __builtin_amdgcn_mfma_f32_16x16x32_bf16(af[mi][kk],        \
                                                                     bf[ni][kk],        \
                                                                     acc[mi][ni], 0, 0, 0); \
  }

  STAGE6(0, 0);
  __syncthreads();
  int buf = 0;
  for (int s = 0; s < 31; ++s) {
    STAGE6(buf ^ 1, s + 1);
    COMPUTE6(buf);
    __syncthreads();
    buf ^= 1;
  }
  COMPUTE6(buf);
#undef STAGE6
#undef COMPUTE6

#pragma unroll
  for (int mi = 0; mi < 2; ++mi) {
    int row = kt * 64 + wr * 32 + mi * 16 + (l >> 4) * 4;
#pragma unroll
    for (int ni = 0; ni < 2; ++ni) {
      int col = dt * 64 + wc * 32 + ni * 16 + (l & 15);
#pragma unroll
      for (int r = 0; r < 4; ++r)
        vpart[((size_t)(ms * 8 + b) * 128 + row + r) * 256 + col] = acc[mi][ni][r];
    }
  }
}

// ---------------- K7: combine partials + bias-part - S*centroid, intra-normalize ----------------
__global__ void k7_intranorm(const float* __restrict__ vpart, const float* __restrict__ colsumW,
                             const float* __restrict__ b_inp, const float* __restrict__ cent,
                             float* __restrict__ out, float* __restrict__ ss1) {
  int k = blockIdx.x;
  int b = blockIdx.y;
  int d = threadIdx.x;
  float S = 0.f, bp = 0.f;
#pragma unroll
  for (int g = 0; g < 8; ++g) {
    float cw = colsumW[b * 1024 + g * 128 + k];
    S += cw;
    bp = fmaf(b_inp[g * 256 + d], cw, bp);
  }
  size_t off = ((size_t)b * 128 + k) * 256 + d;
  float v = vpart[off] + vpart[off + 262144] + bp - S * cent[(size_t)k * 256 + d];
  float ss = v * v;
#pragma unroll
  for (int m = 1; m < 64; m <<= 1) ss += __shfl_xor(ss, m, 64);
  __shared__ float red[4];
  int lane = d & 63, wv = d >> 6;
  if (lane == 0) red[wv] = ss;
  __syncthreads();
  float tot = red[0] + red[1] + red[2] + red[3];
  float rinv = 1.0f / fmaxf(sqrtf(tot), EPSN);
  out[off] = v * rinv;
  if (d == 0) ss1[b * 128 + k] = tot * rinv * rinv;
}

// ---------------- K8: final global L2 norm ----------------
__global__ void k8_finalnorm(const float* __restrict__ ss1, float* __restrict__ out) {
  int b = blockIdx.x;
  int t = threadIdx.x;
  __shared__ float red[256];
  red[t] = (t < 128) ? ss1[b * 128 + t] : 0.f;
  __syncthreads();
  for (int o = 128; o > 0; o >>= 1) {
    if (t < o) red[t] += red[t + o];
    __syncthreads();
  }
  float rinv = 1.0f / fmaxf(sqrtf(red[0]), EPSN);
  float* op = out + (size_t)b * 32768;
  for (int i = t; i < 32768; i += 256) op[i] *= rinv;
}

extern "C" void kernel_launch(void* const* d_in, const int* in_sizes, int n_in,
                              void* d_out, int out_size, void* d_ws, size_t ws_size,
                              hipStream_t stream) {
  const float* x     = (const float*)d_in[0];
  const float* W_inp = (const float*)d_in[1];
  const float* b_inp = (const float*)d_in[2];
  const float* W_g   = (const float*)d_in[3];
  const float* b_g   = (const float*)d_in[4];
  const float* W_gk  = (const float*)d_in[5];
  // b_gk (d_in[6]) cancels in the token-axis softmax — unused.
  const float* cent  = (const float*)d_in[7];
  float* out = (float*)d_out;
  float* ws = (float*)d_ws;

  // workspace layout (float offsets), total ~52.7 MB
  float* ssq8    = ws + 0;        // 32768 [8 cc][4096 tm]
  float* colsumW = ws + 32768;    // 8192
  float* ss1     = ws + 40960;    // 1024
  float* agT     = ws + 41984;    // 32768 [8 g][4096 tm]
  float* bWg     = ws + 74752;    // 64
  float* vpart   = ws + 74816;    // 524288
  float* logitsT = ws + 599104;   // 4194304 [1024 q][4096 tm]
  ushort_t* YcT  = (ushort_t*)logitsT;                    // alias (logitsT dead after k5)
  __hip_bfloat16* xnb = (__hip_bfloat16*)(ws + 4793408);  // 2097152 floats
  ushort_t* wbT  = (ushort_t*)xnb;                        // alias (xnb dead after GEMM1)
  __hip_bfloat16* Wib  = (__hip_bfloat16*)(ws + 6890560); // 1048576
  __hip_bfloat16* Wgkb = (__hip_bfloat16*)(ws + 7939136); // 1048576
  __hip_bfloat16* Ycb  = (__hip_bfloat16*)(ws + 8987712); // 4194304

  k0_ssq<<<512, 256, 0, stream>>>(x, ssq8);
  k1_transpose<<<dim3(16, 64), 256, 0, stream>>>(x, ssq8, xnb);
  kpack2<<<4096, 256, 0, stream>>>(W_inp, W_gk, Wib, Wgkb);
  kbw<<<8, 256, 0, stream>>>(W_g, b_inp, b_g, bWg);
  // GEMM1: Ycb[4096,2048] = xnb @ Wib^T  (centered: bias folded out)
  gemm_bf16_nt_db<0><<<dim3(16, 32), 256, 0, stream>>>((const ushort_t*)xnb, (const ushort_t*)Wib,
                                                       (ushort_t*)Ycb, nullptr, 1024, 2048);
  k3_alpha_g<<<256, 256, 0, stream>>>(Ycb, W_g, bWg, agT);
  // GEMM2 (transposed): logitsT[1024,4096] = Wgkb @ Ycb^T
  gemm_bf16_nt_db<1><<<dim3(32, 8), 256, 0, stream>>>((const ushort_t*)Wgkb, (const ushort_t*)Ycb,
                                                      nullptr, logitsT, 2048, 4096);
  k5_softmax<<<2048, 256, 0, stream>>>(logitsT, agT, colsumW, wbT);
  ktransY<<<dim3(64, 32), 256, 0, stream>>>((const ushort_t*)Ycb, YcT);  // logitsT dead now
  k6_vlad_mfma<<<dim3(8, 2, 8), 256, 0, stream>>>(wbT, YcT, vpart);
  k7_intranorm<<<dim3(128, 8), 256, 0, stream>>>(vpart, colsumW, b_inp, cent, out, ss1);
  k8_finalnorm<<<8, 256, 0, stream>>>(ss1, out);
}

// Round 6
// 136.863 us; speedup vs baseline: 4.9787x; 1.2616x over previous
//
#include <hip/hip_runtime.h>
#include <hip/hip_bf16.h>
#include <math.h>

#define EPSN 1e-12f
typedef unsigned short ushort_t;

typedef float f32x4 __attribute__((ext_vector_type(4)));
typedef short s16x8 __attribute__((ext_vector_type(8)));
typedef unsigned short u16x8 __attribute__((ext_vector_type(8)));

__device__ __forceinline__ void gload_lds16(const void* g, void* l) {
  __builtin_amdgcn_global_load_lds((const __attribute__((address_space(1))) void*)g,
                                   (__attribute__((address_space(3))) void*)l, 16, 0, 0);
}

// ---------------- K0: per-token sum of squares -> 8 partials ----------------
__global__ void k0_ssq(const float* __restrict__ x, float* __restrict__ ssq8) {
  int b8 = blockIdx.x >> 3;
  int cc = blockIdx.x & 7;
  int t = threadIdx.x;
  int s4 = (t & 15) * 4;
  int cg = t >> 4;
  const float* xp = x + (size_t)b8 * 65536 + (size_t)cc * 128 * 64;
  float4 a = {0.f, 0.f, 0.f, 0.f};
#pragma unroll
  for (int j = 0; j < 8; ++j) {
    int c = cg + j * 16;
    float4 v = *(const float4*)(xp + (size_t)c * 64 + s4);
    a.x = fmaf(v.x, v.x, a.x);
    a.y = fmaf(v.y, v.y, a.y);
    a.z = fmaf(v.z, v.z, a.z);
    a.w = fmaf(v.w, v.w, a.w);
  }
  __shared__ float red[16][68];
  *(float4*)&red[cg][s4] = a;
  __syncthreads();
  if (t < 64) {
    float s = 0.f;
#pragma unroll
    for (int g = 0; g < 16; ++g) s += red[g][t];
    ssq8[cc * 4096 + b8 * 64 + t] = s;
  }
}

// ---------------- K1: transpose + scale -> xnb bf16 [tm][c] ----------------
__global__ void k1_transpose(const float* __restrict__ x, const float* __restrict__ ssq8,
                             __hip_bfloat16* __restrict__ xnb) {
  int ct = blockIdx.x;
  int b8 = blockIdx.y;
  int t = threadIdx.x;
  __shared__ float tile[64][65];
  __shared__ float ivs[64];
  if (t < 64) {
    float s = 0.f;
#pragma unroll
    for (int cc = 0; cc < 8; ++cc) s += ssq8[cc * 4096 + b8 * 64 + t];
    ivs[t] = rsqrtf(fmaxf(s, 1e-24f));
  }
  int s = t & 63, cq = t >> 6;
  const float* xp = x + (size_t)b8 * 65536 + (size_t)ct * 64 * 64;
#pragma unroll
  for (int r = 0; r < 16; ++r) {
    int cl = cq * 16 + r;
    tile[cl][s] = xp[cl * 64 + s];
  }
  __syncthreads();
  int cl = t & 63, sq = t >> 6;
#pragma unroll
  for (int r = 0; r < 16; ++r) {
    int smm = sq * 16 + r;
    int tm = b8 * 64 + smm;
    xnb[(size_t)tm * 1024 + ct * 64 + cl] = __float2bfloat16(tile[cl][smm] * ivs[smm]);
  }
}

// ---------------- pack fp32 -> bf16 for both weights + bWg (merged) ----------------
__global__ void kpack2(const float* __restrict__ Wi, const float* __restrict__ Wgk,
                       __hip_bfloat16* __restrict__ oWi, __hip_bfloat16* __restrict__ oWgk,
                       const float* __restrict__ W_g, const float* __restrict__ b_inp,
                       const float* __restrict__ b_g, float* __restrict__ bWg) {
  int bid = blockIdx.x;
  if (bid < 4096) {
    const float* in = (bid < 2048) ? Wi : Wgk;
    __hip_bfloat16* out = (bid < 2048) ? oWi : oWgk;
    int i = ((bid & 2047) * 256 + threadIdx.x) * 4;
    float4 v = *(const float4*)(in + i);
    out[i + 0] = __float2bfloat16(v.x);
    out[i + 1] = __float2bfloat16(v.y);
    out[i + 2] = __float2bfloat16(v.z);
    out[i + 3] = __float2bfloat16(v.w);
  } else {
    int j = bid - 4096;  // 0..7
    const float* row = W_g + (size_t)j * 2048;
    int t = threadIdx.x;
    float s = 0.f;
    for (int c = t; c < 2048; c += 256) s = fmaf(b_inp[c], row[c], s);
    __shared__ float red[256];
    red[t] = s;
    __syncthreads();
    for (int o = 128; o > 0; o >>= 1) {
      if (t < o) red[t] += red[t + o];
      __syncthreads();
    }
    if (t == 0) bWg[j] = red[0] + b_g[j];
  }
}

// ---------------- bf16 MFMA NT GEMM: 128x128, BK=64, 8 waves, dbuf, swizzle, counted vmcnt ----
// C[M,N] = A[M,K] @ B[N,K]^T. OUT: 0 = bf16, 1 = f32.
// LDS 16B-slot swizzle: slot p of row r holds logical slot p ^ (r&7); inverse applied to
// per-lane GLOBAL source (linear LDS dest), swizzle applied on ds_read (rule #21).
template <int OUT>
__launch_bounds__(512, 4)
__global__ void gemm_bf16_nt_db(const ushort_t* __restrict__ A, const ushort_t* __restrict__ B,
                                ushort_t* __restrict__ Cb, float* __restrict__ Cf,
                                int K, int N) {
  __shared__ alignas(16) ushort_t Ash[2][8192];
  __shared__ alignas(16) ushort_t Bsh[2][8192];
  const int tid = threadIdx.x;
  const int m0 = blockIdx.y * 128, n0 = blockIdx.x * 128;
  const int w = tid >> 6, l = tid & 63;
  const int wr = w >> 2, wc = w & 3;  // 2 x 4 wave grid; per-wave 64x32 output
  // staging: pass p covers rows p*64 + w*8 + (l>>3); lane slot l&7, swizzled by row&7 = l>>3
  const int srow = w * 8 + (l >> 3);
  const int ksw = ((l & 7) ^ (l >> 3)) * 8;
  const ushort_t* Ag0 = A + (size_t)(m0 + srow) * K + ksw;
  const ushort_t* Ag1 = A + (size_t)(m0 + 64 + srow) * K + ksw;
  const ushort_t* Bg0 = B + (size_t)(n0 + srow) * K + ksw;
  const ushort_t* Bg1 = B + (size_t)(n0 + 64 + srow) * K + ksw;
  const int l0 = w * 512;          // pass0 LDS elem base (lane-linear)
  const int l1 = 4096 + w * 512;   // pass1

  f32x4 acc[4][2];
#pragma unroll
  for (int i = 0; i < 4; ++i)
#pragma unroll
    for (int j = 0; j < 2; ++j) acc[i][j] = (f32x4){0.f, 0.f, 0.f, 0.f};

  const int sw = l & 7, qq = l >> 4;

#define STAGE(buf, k0)                              \
  {                                                 \
    gload_lds16(Ag0 + (k0), &Ash[buf][l0]);         \
    gload_lds16(Ag1 + (k0), &Ash[buf][l1]);         \
    gload_lds16(Bg0 + (k0), &Bsh[buf][l0]);         \
    gload_lds16(Bg1 + (k0), &Bsh[buf][l1]);         \
  }

#define COMPUTE(buf)                                                                     \
  {                                                                                      \
    s16x8 af[4][2], bf[2][2];                                                            \
    _Pragma("unroll") for (int kk = 0; kk < 2; ++kk) {                                   \
      int slot = (((kk << 2) + qq) ^ sw) * 8;                                            \
      _Pragma("unroll") for (int mi = 0; mi < 4; ++mi)                                   \
          af[mi][kk] = *(const s16x8*)&Ash[buf][(wr * 64 + mi * 16 + (l & 15)) * 64 +    \
                                               slot];                                    \
      _Pragma("unroll") for (int ni = 0; ni < 2; ++ni)                                   \
          bf[ni][kk] = *(const s16x8*)&Bsh[buf][(wc * 32 + ni * 16 + (l & 15)) * 64 +    \
                                               slot];                                    \
    }                                                                                    \
    _Pragma("unroll") for (int kk = 0; kk < 2; ++kk)                                     \
        _Pragma("unroll") for (int mi = 0; mi < 4; ++mi)                                 \
            _Pragma("unroll") for (int ni = 0; ni < 2; ++ni)                             \
                acc[mi][ni] = __builtin_amdgcn_mfma_f32_16x16x32_bf16(af[mi][kk],        \
                                                                     bf[ni][kk],        \
                                                                     acc[mi][ni], 0, 0, 0); \
  }

  const int nt = K >> 6;
  STAGE(0, 0);
  int buf = 0;
  for (int t = 0; t < nt - 1; ++t) {
    STAGE(buf ^ 1, (t + 1) << 6);
    asm volatile("s_waitcnt vmcnt(4)" ::: "memory");  // prev buf's 4 landed; new 4 in flight
    __builtin_amdgcn_s_barrier();
    asm volatile("" ::: "memory");
    COMPUTE(buf);
    asm volatile("" ::: "memory");
    __builtin_amdgcn_s_barrier();
    buf ^= 1;
  }
  asm volatile("s_waitcnt vmcnt(0)" ::: "memory");
  __builtin_amdgcn_s_barrier();
  asm volatile("" ::: "memory");
  COMPUTE(buf);
#undef STAGE
#undef COMPUTE

#pragma unroll
  for (int mi = 0; mi < 4; ++mi) {
    int row = m0 + wr * 64 + mi * 16 + (l >> 4) * 4;
#pragma unroll
    for (int ni = 0; ni < 2; ++ni) {
      int col = n0 + wc * 32 + ni * 16 + (l & 15);
#pragma unroll
      for (int r = 0; r < 4; ++r) {
        if constexpr (OUT == 0) {
          __hip_bfloat16 hb = __float2bfloat16(acc[mi][ni][r]);
          Cb[(size_t)(row + r) * N + col] = *(ushort_t*)&hb;
        } else {
          Cf[(size_t)(row + r) * N + col] = acc[mi][ni][r];
        }
      }
    }
  }
}

// ---------------- K3: agT[g][tm] = sigmoid(Yc @ W_g^T + bWg) ----------------
__global__ void k3_alpha_g(const __hip_bfloat16* __restrict__ Yc, const float* __restrict__ Wg,
                           const float* __restrict__ bWg, float* __restrict__ agT) {
  __shared__ float wgs[8 * 2048];
  int t = threadIdx.x;
  for (int r = 0; r < 64; ++r) wgs[t + r * 256] = Wg[t + r * 256];
  __syncthreads();
  int team = t >> 4, i = t & 15;
  int tok = blockIdx.x * 16 + team;
  const __hip_bfloat16* yp = Yc + (size_t)tok * 2048;
  float acc[8] = {0, 0, 0, 0, 0, 0, 0, 0};
  for (int c0 = i * 8; c0 < 2048; c0 += 128) {
    u16x8 y8 = *(const u16x8*)(yp + c0);
#pragma unroll
    for (int j = 0; j < 8; ++j) {
      float yf = __uint_as_float(((unsigned)y8[j]) << 16);
#pragma unroll
      for (int g = 0; g < 8; ++g)
        acc[g] = fmaf(yf, wgs[g * 2048 + c0 + j], acc[g]);
    }
  }
#pragma unroll
  for (int g = 0; g < 8; ++g) {
    acc[g] += __shfl_xor(acc[g], 1, 16);
    acc[g] += __shfl_xor(acc[g], 2, 16);
    acc[g] += __shfl_xor(acc[g], 4, 16);
    acc[g] += __shfl_xor(acc[g], 8, 16);
  }
  if (i < 8) {
    float v = 0.f;
#pragma unroll
    for (int g = 0; g < 8; ++g)
      if (g == i) v = acc[g];
    v += bWg[i];
    agT[(size_t)i * 4096 + tok] = 1.0f / (1.0f + expf(-v));
  }
}

// ---------------- K5: row softmax over tokens, one wave per (q,b) ----------------
__launch_bounds__(256)
__global__ void k5_softmax(const float* __restrict__ logitsT, const float* __restrict__ agT,
                           float* __restrict__ colsumW, ushort_t* __restrict__ wbT) {
  int wv = (blockIdx.x << 2) + (threadIdx.x >> 6);
  int q = wv >> 3, b = wv & 7;
  int l = threadIdx.x & 63;
  int g = q >> 7;
  size_t base = (size_t)q * 4096 + b * 512 + l * 8;
  float4 v0 = *(const float4*)(logitsT + base);
  float4 v1 = *(const float4*)(logitsT + base + 4);
  float vs[8] = {v0.x, v0.y, v0.z, v0.w, v1.x, v1.y, v1.z, v1.w};
  float M = vs[0];
#pragma unroll
  for (int i = 1; i < 8; ++i) M = fmaxf(M, vs[i]);
#pragma unroll
  for (int m = 1; m < 64; m <<= 1) M = fmaxf(M, __shfl_xor(M, m, 64));
  float e[8], S = 0.f;
#pragma unroll
  for (int i = 0; i < 8; ++i) {
    e[i] = expf(vs[i] - M);
    S += e[i];
  }
#pragma unroll
  for (int m = 1; m < 64; m <<= 1) S += __shfl_xor(S, m, 64);
  float R = 1.0f / S;
  size_t abase = (size_t)g * 4096 + b * 512 + l * 8;
  float4 a0 = *(const float4*)(agT + abase);
  float4 a1 = *(const float4*)(agT + abase + 4);
  float ag[8] = {a0.x, a0.y, a0.z, a0.w, a1.x, a1.y, a1.z, a1.w};
  float wv8[8], wsum = 0.f;
#pragma unroll
  for (int i = 0; i < 8; ++i) {
    wv8[i] = e[i] * R * ag[i];
    wsum += wv8[i];
  }
#pragma unroll
  for (int m = 1; m < 64; m <<= 1) wsum += __shfl_xor(wsum, m, 64);
  if (l == 0) colsumW[b * 1024 + q] = wsum;
  u16x8 o;
#pragma unroll
  for (int i = 0; i < 8; ++i) {
    __hip_bfloat16 hb = __float2bfloat16(wv8[i]);
    o[i] = *(ushort_t*)&hb;
  }
  *(u16x8*)(wbT + base) = o;
}

// ---------------- ktransY: Ycb[4096 m][2048 c] -> YcT[2048 c][4096 m] ----------------
__global__ void ktransY(const ushort_t* __restrict__ Y, ushort_t* __restrict__ YT) {
  int mt = blockIdx.x;
  int ct = blockIdx.y;
  __shared__ ushort_t tile[64][80];
  int t = threadIdx.x;
  int r = t >> 2, cseg = (t & 3) * 16;
  const ushort_t* src = Y + (size_t)(mt * 64 + r) * 2048 + ct * 64 + cseg;
  *(u16x8*)&tile[r][cseg] = *(const u16x8*)src;
  *(u16x8*)&tile[r][cseg + 8] = *(const u16x8*)(src + 8);
  __syncthreads();
  int cl = t >> 2, mseg = (t & 3) * 16;
  u16x8 o0, o1;
#pragma unroll
  for (int j = 0; j < 8; ++j) o0[j] = tile[mseg + j][cl];
#pragma unroll
  for (int j = 0; j < 8; ++j) o1[j] = tile[mseg + 8 + j][cl];
  ushort_t* dst = YT + (size_t)(ct * 64 + cl) * 4096 + mt * 64 + mseg;
  *(u16x8*)dst = o0;
  *(u16x8*)(dst + 8) = o1;
}

// ---------------- K6: VLAD einsum via MFMA, 64x64 tile, m-split 4, counted vmcnt ----------------
__launch_bounds__(256)
__global__ void k6_vlad_mfma(const ushort_t* __restrict__ wbT, const ushort_t* __restrict__ YcT,
                             float* __restrict__ vpart) {
  int kt = blockIdx.x >> 2, dt = blockIdx.x & 3;
  int ms = blockIdx.y, b = blockIdx.z;  // ms 0..3 (128 m each)
  __shared__ alignas(16) ushort_t Ash[2][4096];
  __shared__ alignas(16) ushort_t Bsh[2][4096];
  const int tid = threadIdx.x;
  const int w = tid >> 6, l = tid & 63;
  const int wr = w >> 1, wc = w & 1;
  const int crow = l >> 3;
  const int ksw = ((l & 7) ^ crow) * 8;

  const ushort_t* Ap[2];
  const ushort_t* Bp[2];
  int loff[2];
#pragma unroll
  for (int c = 0; c < 2; ++c) {
    int chunk = w * 2 + c;  // 0..7
    Ap[c] = wbT + (size_t)(kt * 64 + chunk * 8 + crow) * 4096 + b * 512 + ms * 128 + ksw;
    Bp[c] = YcT + (size_t)(dt * 64 + chunk * 8 + crow) * 4096 + b * 512 + ms * 128 + ksw;
    loff[c] = chunk * 512;
  }

  f32x4 acc[2][2];
#pragma unroll
  for (int i = 0; i < 2; ++i)
#pragma unroll
    for (int j = 0; j < 2; ++j) acc[i][j] = (f32x4){0.f, 0.f, 0.f, 0.f};

  const int sw = l & 7, qq = l >> 4;

#define STAGE6(buf, s)                                                       \
  {                                                                          \
    size_t offA = (size_t)((s) >> 1) * 524288 + ((s)&1) * 64;                \
    size_t offB = (size_t)((s) >> 1) * 1048576 + ((s)&1) * 64;               \
    gload_lds16(Ap[0] + offA, &Ash[buf][loff[0]]);                           \
    gload_lds16(Ap[1] + offA, &Ash[buf][loff[1]]);                           \
    gload_lds16(Bp[0] + offB, &Bsh[buf][loff[0]]);                           \
    gload_lds16(Bp[1] + offB, &Bsh[buf][loff[1]]);                           \
  }

#define COMPUTE6(buf)                                                                    \
  {                                                                                      \
    s16x8 af[2][2], bf[2][2];                                                            \
    _Pragma("unroll") for (int kk = 0; kk < 2; ++kk) {                                   \
      int slot = (((kk << 2) + qq) ^ sw) * 8;                                            \
      _Pragma("unroll") for (int mi = 0; mi < 2; ++mi) {                                 \
        af[mi][kk] = *(const s16x8*)&Ash[buf][(wr * 32 + mi * 16 + (l & 15)) * 64 +      \
                                             slot];                                     \
        bf[mi][kk] = *(const s16x8*)&Bsh[buf][(wc * 32 + mi * 16 + (l & 15)) * 64 +      \
                                             slot];                                     \
      }                                                                                  \
    }                                                                                    \
    _Pragma("unroll") for (int kk = 0; kk < 2; ++kk)                                     \
        _Pragma("unroll") for (int mi = 0; mi < 2; ++mi)                                 \
            _Pragma("unroll") for (int ni = 0; ni < 2; ++ni)                             \
                acc[mi][ni] = __builtin_amdgcn_mfma_f32_16x16x32_bf16(af[mi][kk],        \
                                                                     bf[ni][kk],        \
                                                                     acc[mi][ni], 0, 0, 0); \
  }

  STAGE6(0, 0);
  int buf = 0;
  for (int s = 0; s < 15; ++s) {  // 16 steps: 8 g x 2 m-halves (BK=64)
    STAGE6(buf ^ 1, s + 1);
    asm volatile("s_waitcnt vmcnt(4)" ::: "memory");
    __builtin_amdgcn_s_barrier();
    asm volatile("" ::: "memory");
    COMPUTE6(buf);
    asm volatile("" ::: "memory");
    __builtin_amdgcn_s_barrier();
    buf ^= 1;
  }
  asm volatile("s_waitcnt vmcnt(0)" ::: "memory");
  __builtin_amdgcn_s_barrier();
  asm volatile("" ::: "memory");
  COMPUTE6(buf);
#undef STAGE6
#undef COMPUTE6

#pragma unroll
  for (int mi = 0; mi < 2; ++mi) {
    int row = kt * 64 + wr * 32 + mi * 16 + (l >> 4) * 4;
#pragma unroll
    for (int ni = 0; ni < 2; ++ni) {
      int col = dt * 64 + wc * 32 + ni * 16 + (l & 15);
#pragma unroll
      for (int r = 0; r < 4; ++r)
        vpart[((size_t)(ms * 8 + b) * 128 + row + r) * 256 + col] = acc[mi][ni][r];
    }
  }
}

// ---------------- K7: combine 4 partials + bias-part - S*centroid, intra-normalize ----------------
__global__ void k7_intranorm(const float* __restrict__ vpart, const float* __restrict__ colsumW,
                             const float* __restrict__ b_inp, const float* __restrict__ cent,
                             float* __restrict__ out, float* __restrict__ ss1) {
  int k = blockIdx.x;
  int b = blockIdx.y;
  int d = threadIdx.x;
  float S = 0.f, bp = 0.f;
#pragma unroll
  for (int g = 0; g < 8; ++g) {
    float cw = colsumW[b * 1024 + g * 128 + k];
    S += cw;
    bp = fmaf(b_inp[g * 256 + d], cw, bp);
  }
  size_t off = ((size_t)b * 128 + k) * 256 + d;
  float v = vpart[off] + vpart[off + 262144] + vpart[off + 524288] + vpart[off + 786432]
            + bp - S * cent[(size_t)k * 256 + d];
  float ss = v * v;
#pragma unroll
  for (int m = 1; m < 64; m <<= 1) ss += __shfl_xor(ss, m, 64);
  __shared__ float red[4];
  int lane = d & 63, wv = d >> 6;
  if (lane == 0) red[wv] = ss;
  __syncthreads();
  float tot = red[0] + red[1] + red[2] + red[3];
  float rinv = 1.0f / fmaxf(sqrtf(tot), EPSN);
  out[off] = v * rinv;
  if (d == 0) ss1[b * 128 + k] = tot * rinv * rinv;
}

// ---------------- K8: final global L2 norm ----------------
__global__ void k8_finalnorm(const float* __restrict__ ss1, float* __restrict__ out) {
  int b = blockIdx.x;
  int t = threadIdx.x;
  __shared__ float red[256];
  red[t] = (t < 128) ? ss1[b * 128 + t] : 0.f;
  __syncthreads();
  for (int o = 128; o > 0; o >>= 1) {
    if (t < o) red[t] += red[t + o];
    __syncthreads();
  }
  float rinv = 1.0f / fmaxf(sqrtf(red[0]), EPSN);
  float* op = out + (size_t)b * 32768;
  for (int i = t; i < 32768; i += 256) op[i] *= rinv;
}

extern "C" void kernel_launch(void* const* d_in, const int* in_sizes, int n_in,
                              void* d_out, int out_size, void* d_ws, size_t ws_size,
                              hipStream_t stream) {
  const float* x     = (const float*)d_in[0];
  const float* W_inp = (const float*)d_in[1];
  const float* b_inp = (const float*)d_in[2];
  const float* W_g   = (const float*)d_in[3];
  const float* b_g   = (const float*)d_in[4];
  const float* W_gk  = (const float*)d_in[5];
  // b_gk (d_in[6]) cancels in the token-axis softmax — unused.
  const float* cent  = (const float*)d_in[7];
  float* out = (float*)d_out;
  float* ws = (float*)d_ws;

  // workspace layout (float offsets), total ~54.8 MB
  float* ssq8    = ws + 0;         // 32768 [8 cc][4096 tm]
  float* colsumW = ws + 32768;     // 8192
  float* ss1     = ws + 40960;     // 1024
  float* agT     = ws + 41984;     // 32768 [8 g][4096 tm]
  float* bWg     = ws + 74752;     // 64
  float* vpart   = ws + 74816;     // 1048576 (4 partials)
  float* logitsT = ws + 1123392;   // 4194304 [1024 q][4096 tm]
  ushort_t* YcT  = (ushort_t*)logitsT;                    // alias (logitsT dead after k5)
  __hip_bfloat16* xnb = (__hip_bfloat16*)(ws + 5317696);  // 2097152 floats
  ushort_t* wbT  = (ushort_t*)xnb;                        // alias (xnb dead after GEMM1)
  __hip_bfloat16* Wib  = (__hip_bfloat16*)(ws + 7414848); // 1048576
  __hip_bfloat16* Wgkb = (__hip_bfloat16*)(ws + 8463424); // 1048576
  __hip_bfloat16* Ycb  = (__hip_bfloat16*)(ws + 9512000); // 4194304

  k0_ssq<<<512, 256, 0, stream>>>(x, ssq8);
  k1_transpose<<<dim3(16, 64), 256, 0, stream>>>(x, ssq8, xnb);
  kpack2<<<4104, 256, 0, stream>>>(W_inp, W_gk, Wib, Wgkb, W_g, b_inp, b_g, bWg);
  // GEMM1: Ycb[4096,2048] = xnb @ Wib^T  (centered: bias folded out)
  gemm_bf16_nt_db<0><<<dim3(16, 32), 512, 0, stream>>>((const ushort_t*)xnb, (const ushort_t*)Wib,
                                                       (ushort_t*)Ycb, nullptr, 1024, 2048);
  k3_alpha_g<<<256, 256, 0, stream>>>(Ycb, W_g, bWg, agT);
  // GEMM2 (transposed): logitsT[1024,4096] = Wgkb @ Ycb^T
  gemm_bf16_nt_db<1><<<dim3(32, 8), 512, 0, stream>>>((const ushort_t*)Wgkb, (const ushort_t*)Ycb,
                                                      nullptr, logitsT, 2048, 4096);
  k5_softmax<<<2048, 256, 0, stream>>>(logitsT, agT, colsumW, wbT);
  ktransY<<<dim3(64, 32), 256, 0, stream>>>((const ushort_t*)Ycb, YcT);  // logitsT dead now
  k6_vlad_mfma<<<dim3(8, 4, 8), 256, 0, stream>>>(wbT, YcT, vpart);
  k7_intranorm<<<dim3(128, 8), 256, 0, stream>>>(vpart, colsumW, b_inp, cent, out, ss1);
  k8_finalnorm<<<8, 256, 0, stream>>>(ss1, out);
}

// Round 8
// 122.073 us; speedup vs baseline: 5.5819x; 1.1212x over previous
//
#include <hip/hip_runtime.h>
#include <hip/hip_bf16.h>
#include <math.h>

#define EPSN 1e-12f
typedef unsigned short ushort_t;

typedef float f32x4 __attribute__((ext_vector_type(4)));
typedef short s16x8 __attribute__((ext_vector_type(8)));
typedef unsigned short u16x8 __attribute__((ext_vector_type(8)));
typedef unsigned short u16x4 __attribute__((ext_vector_type(4)));

__device__ __forceinline__ void gload_lds16(const void* g, void* l) {
  __builtin_amdgcn_global_load_lds((const __attribute__((address_space(1))) void*)g,
                                   (__attribute__((address_space(3))) void*)l, 16, 0, 0);
}

// ---------------- K0: per-token sum of squares -> 8 partials ----------------
__global__ void k0_ssq(const float* __restrict__ x, float* __restrict__ ssq8) {
  int b8 = blockIdx.x >> 3;
  int cc = blockIdx.x & 7;
  int t = threadIdx.x;
  int s4 = (t & 15) * 4;
  int cg = t >> 4;
  const float* xp = x + (size_t)b8 * 65536 + (size_t)cc * 128 * 64;
  float4 a = {0.f, 0.f, 0.f, 0.f};
#pragma unroll
  for (int j = 0; j < 8; ++j) {
    int c = cg + j * 16;
    float4 v = *(const float4*)(xp + (size_t)c * 64 + s4);
    a.x = fmaf(v.x, v.x, a.x);
    a.y = fmaf(v.y, v.y, a.y);
    a.z = fmaf(v.z, v.z, a.z);
    a.w = fmaf(v.w, v.w, a.w);
  }
  __shared__ float red[16][68];
  *(float4*)&red[cg][s4] = a;
  __syncthreads();
  if (t < 64) {
    float s = 0.f;
#pragma unroll
    for (int g = 0; g < 16; ++g) s += red[g][t];
    ssq8[cc * 4096 + b8 * 64 + t] = s;
  }
}

// ---------------- K1: transpose + scale -> xnb bf16 [tm][c] ----------------
__global__ void k1_transpose(const float* __restrict__ x, const float* __restrict__ ssq8,
                             __hip_bfloat16* __restrict__ xnb) {
  int ct = blockIdx.x;
  int b8 = blockIdx.y;
  int t = threadIdx.x;
  __shared__ float tile[64][65];
  __shared__ float ivs[64];
  if (t < 64) {
    float s = 0.f;
#pragma unroll
    for (int cc = 0; cc < 8; ++cc) s += ssq8[cc * 4096 + b8 * 64 + t];
    ivs[t] = rsqrtf(fmaxf(s, 1e-24f));
  }
  int s = t & 63, cq = t >> 6;
  const float* xp = x + (size_t)b8 * 65536 + (size_t)ct * 64 * 64;
#pragma unroll
  for (int r = 0; r < 16; ++r) {
    int cl = cq * 16 + r;
    tile[cl][s] = xp[cl * 64 + s];
  }
  __syncthreads();
  int cl = t & 63, sq = t >> 6;
#pragma unroll
  for (int r = 0; r < 16; ++r) {
    int smm = sq * 16 + r;
    int tm = b8 * 64 + smm;
    xnb[(size_t)tm * 1024 + ct * 64 + cl] = __float2bfloat16(tile[cl][smm] * ivs[smm]);
  }
}

// ---------------- kpack2: pack Wib + Wgkx (W_gk rows 0-1023, W_g rows 1024-1031,
//                  zeros 1032-1151) + bWg ----------------
__global__ void kpack2(const float* __restrict__ Wi, const float* __restrict__ Wgk,
                       const float* __restrict__ W_g, const float* __restrict__ b_inp,
                       const float* __restrict__ b_g, __hip_bfloat16* __restrict__ oWi,
                       __hip_bfloat16* __restrict__ oWx, float* __restrict__ bWg) {
  int bid = blockIdx.x;
  int t = threadIdx.x;
  if (bid < 2048) {
    int i = (bid * 256 + t) * 4;
    float4 v = *(const float4*)(Wi + i);
    oWi[i + 0] = __float2bfloat16(v.x);
    oWi[i + 1] = __float2bfloat16(v.y);
    oWi[i + 2] = __float2bfloat16(v.z);
    oWi[i + 3] = __float2bfloat16(v.w);
  } else if (bid < 4096) {
    int i = ((bid - 2048) * 256 + t) * 4;
    float4 v = *(const float4*)(Wgk + i);
    oWx[i + 0] = __float2bfloat16(v.x);
    oWx[i + 1] = __float2bfloat16(v.y);
    oWx[i + 2] = __float2bfloat16(v.z);
    oWx[i + 3] = __float2bfloat16(v.w);
  } else if (bid < 4112) {
    int i = (bid - 4096) * 1024 + t * 4;  // 16 blocks x 1024 = 16384 = 8x2048
    float4 v = *(const float4*)(W_g + i);
    __hip_bfloat16* o = oWx + 1024 * 2048 + i;
    o[0] = __float2bfloat16(v.x);
    o[1] = __float2bfloat16(v.y);
    o[2] = __float2bfloat16(v.z);
    o[3] = __float2bfloat16(v.w);
  } else if (bid < 4352) {
    int i = (bid - 4112) * 1024 + t * 4;  // 240 blocks -> 120 zero rows
    ushort_t* o = (ushort_t*)(oWx + 1032 * 2048) + i;
    *(u16x4*)o = (u16x4){0, 0, 0, 0};
  } else {
    int j = bid - 4352;  // 0..7
    const float* row = W_g + (size_t)j * 2048;
    float s = 0.f;
    for (int c = t; c < 2048; c += 256) s = fmaf(b_inp[c], row[c], s);
    __shared__ float red[256];
    red[t] = s;
    __syncthreads();
    for (int o = 128; o > 0; o >>= 1) {
      if (t < o) red[t] += red[t + o];
      __syncthreads();
    }
    if (t == 0) bWg[j] = red[0] + b_g[j];
  }
}

// ---------------- bf16 MFMA NT GEMM: 128x128, BK=64, 8 waves, dbuf, swizzle, counted vmcnt ----
// OUT=0: write Cb (bf16, row-major) AND Tt (bf16 transposed [N][4096]) via LDS bounce.
// OUT=1: write Cf (f32).  OUT=2: write Cb (bf16) only.
template <int OUT>
__launch_bounds__(512, 4)
__global__ void gemm_bf16_nt_db(const ushort_t* __restrict__ A, const ushort_t* __restrict__ B,
                                ushort_t* __restrict__ Cb, float* __restrict__ Cf,
                                ushort_t* __restrict__ Tt, int K, int N) {
  __shared__ alignas(16) ushort_t SH[32768];  // 64 KB: Ash[2] | Bsh[2]
  const int tid = threadIdx.x;
  const int m0 = blockIdx.y * 128, n0 = blockIdx.x * 128;
  const int w = tid >> 6, l = tid & 63;
  const int wr = w >> 2, wc = w & 3;  // 2x4 wave grid; per-wave 64m x 32n
  const int srow = w * 8 + (l >> 3);
  const int ksw = ((l & 7) ^ (l >> 3)) * 8;
  const ushort_t* Ag0 = A + (size_t)(m0 + srow) * K + ksw;
  const ushort_t* Ag1 = A + (size_t)(m0 + 64 + srow) * K + ksw;
  const ushort_t* Bg0 = B + (size_t)(n0 + srow) * K + ksw;
  const ushort_t* Bg1 = B + (size_t)(n0 + 64 + srow) * K + ksw;
  const int l0 = w * 512;
  const int l1 = 4096 + w * 512;

  f32x4 acc[4][2];
#pragma unroll
  for (int i = 0; i < 4; ++i)
#pragma unroll
    for (int j = 0; j < 2; ++j) acc[i][j] = (f32x4){0.f, 0.f, 0.f, 0.f};

  const int sw = l & 7, qq = l >> 4;

#define ASH(buf) (SH + (buf)*8192)
#define BSH(buf) (SH + 16384 + (buf)*8192)
#define STAGE(buf, k0)                               \
  {                                                  \
    gload_lds16(Ag0 + (k0), ASH(buf) + l0);          \
    gload_lds16(Ag1 + (k0), ASH(buf) + l1);          \
    gload_lds16(Bg0 + (k0), BSH(buf) + l0);          \
    gload_lds16(Bg1 + (k0), BSH(buf) + l1);          \
  }

#define COMPUTE(buf)                                                                     \
  {                                                                                      \
    s16x8 af[4][2], bf[2][2];                                                            \
    _Pragma("unroll") for (int kk = 0; kk < 2; ++kk) {                                   \
      int slot = (((kk << 2) + qq) ^ sw) * 8;                                            \
      _Pragma("unroll") for (int mi = 0; mi < 4; ++mi)                                   \
          af[mi][kk] = *(const s16x8*)&ASH(buf)[(wr * 64 + mi * 16 + (l & 15)) * 64 +    \
                                               slot];                                   \
      _Pragma("unroll") for (int ni = 0; ni < 2; ++ni)                                   \
          bf[ni][kk] = *(const s16x8*)&BSH(buf)[(wc * 32 + ni * 16 + (l & 15)) * 64 +    \
                                               slot];                                   \
    }                                                                                    \
    _Pragma("unroll") for (int kk = 0; kk < 2; ++kk)                                     \
        _Pragma("unroll") for (int mi = 0; mi < 4; ++mi)                                 \
            _Pragma("unroll") for (int ni = 0; ni < 2; ++ni)                             \
                acc[mi][ni] = __builtin_amdgcn_mfma_f32_16x16x32_bf16(af[mi][kk],        \
                                                                     bf[ni][kk],        \
                                                                     acc[mi][ni], 0, 0, 0); \
  }

  const int nt = K >> 6;
  STAGE(0, 0);
  int buf = 0;
  for (int t = 0; t < nt - 1; ++t) {
    STAGE(buf ^ 1, (t + 1) << 6);
    asm volatile("s_waitcnt vmcnt(4)" ::: "memory");
    __builtin_amdgcn_s_barrier();
    asm volatile("" ::: "memory");
    COMPUTE(buf);
    asm volatile("" ::: "memory");
    __builtin_amdgcn_s_barrier();
    buf ^= 1;
  }
  asm volatile("s_waitcnt vmcnt(0)" ::: "memory");
  __builtin_amdgcn_s_barrier();
  asm volatile("" ::: "memory");
  COMPUTE(buf);
#undef STAGE
#undef COMPUTE
#undef ASH
#undef BSH

  if constexpr (OUT == 1) {
#pragma unroll
    for (int mi = 0; mi < 4; ++mi) {
      int row = m0 + wr * 64 + mi * 16 + (l >> 4) * 4;
#pragma unroll
      for (int ni = 0; ni < 2; ++ni) {
        int col = n0 + wc * 32 + ni * 16 + (l & 15);
#pragma unroll
        for (int r = 0; r < 4; ++r)
          Cf[(size_t)(row + r) * N + col] = acc[mi][ni][r];
      }
    }
  } else if constexpr (OUT == 2) {
#pragma unroll
    for (int mi = 0; mi < 4; ++mi) {
      int row = m0 + wr * 64 + mi * 16 + (l >> 4) * 4;
#pragma unroll
      for (int ni = 0; ni < 2; ++ni) {
        int col = n0 + wc * 32 + ni * 16 + (l & 15);
#pragma unroll
        for (int r = 0; r < 4; ++r) {
          __hip_bfloat16 hb = __float2bfloat16(acc[mi][ni][r]);
          Cb[(size_t)(row + r) * N + col] = *(ushort_t*)&hb;
        }
      }
    }
  } else {
    // dual write: Cb row-major + Tt transposed, via per-wave LDS tile [32c][72]
    __syncthreads();  // all waves done reading SH
    ushort_t* T = SH + w * 2304;
#pragma unroll
    for (int mi = 0; mi < 4; ++mi) {
      int m = mi * 16 + (l >> 4) * 4;
#pragma unroll
      for (int ni = 0; ni < 2; ++ni) {
        int c = ni * 16 + (l & 15);
        u16x4 pk;
#pragma unroll
        for (int r = 0; r < 4; ++r) {
          __hip_bfloat16 hb = __float2bfloat16(acc[mi][ni][r]);
          pk[r] = *(ushort_t*)&hb;
        }
        *(u16x4*)&T[c * 72 + m] = pk;
        int row = m0 + wr * 64 + m;
        int col = n0 + wc * 32 + c;
#pragma unroll
        for (int r = 0; r < 4; ++r) Cb[(size_t)(row + r) * N + col] = pk[r];
      }
    }
    int cb = l >> 3, mc = (l & 7) ^ cb;
#pragma unroll
    for (int j = 0; j < 4; ++j) {
      int c = cb + j * 8;
      u16x8 v = *(const u16x8*)&T[c * 72 + mc * 8];
      *(u16x8*)&Tt[(size_t)(n0 + wc * 32 + c) * 4096 + m0 + wr * 64 + mc * 8] = v;
    }
  }
}

// ---------------- K5: row softmax over tokens + gate sigmoid, one wave per (q,b) ----------------
// logitsTb bf16 [1152 q][4096 tm]: rows 0-1023 cluster logits, rows 1024-1031 gate logits.
__launch_bounds__(256)
__global__ void k5_softmax(const ushort_t* __restrict__ logitsTb, const float* __restrict__ bWg,
                           float* __restrict__ colsumW, ushort_t* __restrict__ wbT) {
  int wv = (blockIdx.x << 2) + (threadIdx.x >> 6);
  int q = wv >> 3, b = wv & 7;
  int l = threadIdx.x & 63;
  int g = q >> 7;
  size_t base = (size_t)q * 4096 + b * 512 + l * 8;
  u16x8 v8 = *(const u16x8*)(logitsTb + base);
  float vs[8];
#pragma unroll
  for (int i = 0; i < 8; ++i) vs[i] = __uint_as_float(((unsigned)v8[i]) << 16);
  float M = vs[0];
#pragma unroll
  for (int i = 1; i < 8; ++i) M = fmaxf(M, vs[i]);
#pragma unroll
  for (int m = 1; m < 64; m <<= 1) M = fmaxf(M, __shfl_xor(M, m, 64));
  float e[8], S = 0.f;
#pragma unroll
  for (int i = 0; i < 8; ++i) {
    e[i] = expf(vs[i] - M);
    S += e[i];
  }
#pragma unroll
  for (int m = 1; m < 64; m <<= 1) S += __shfl_xor(S, m, 64);
  float R = 1.0f / S;
  u16x8 g8 = *(const u16x8*)(logitsTb + (size_t)(1024 + g) * 4096 + b * 512 + l * 8);
  float bg = bWg[g];
  float wv8[8], wsum = 0.f;
#pragma unroll
  for (int i = 0; i < 8; ++i) {
    float gl = __uint_as_float(((unsigned)g8[i]) << 16);
    float ag = 1.0f / (1.0f + expf(-(gl + bg)));
    wv8[i] = e[i] * R * ag;
    wsum += wv8[i];
  }
#pragma unroll
  for (int m = 1; m < 64; m <<= 1) wsum += __shfl_xor(wsum, m, 64);
  if (l == 0) colsumW[b * 1024 + q] = wsum;
  u16x8 o;
#pragma unroll
  for (int i = 0; i < 8; ++i) {
    __hip_bfloat16 hb = __float2bfloat16(wv8[i]);
    o[i] = *(ushort_t*)&hb;
  }
  *(u16x8*)(wbT + base) = o;
}

// ---------------- K6: VLAD einsum via MFMA, 64x64 tile, m-split 8, counted vmcnt ----------------
__launch_bounds__(256)
__global__ void k6_vlad_mfma(const ushort_t* __restrict__ wbT, const ushort_t* __restrict__ YcT,
                             float* __restrict__ vpart) {
  int kt = blockIdx.x >> 2, dt = blockIdx.x & 3;
  int ms = blockIdx.y, b = blockIdx.z;  // ms 0..7 (64 m each)
  __shared__ alignas(16) ushort_t Ash[2][4096];
  __shared__ alignas(16) ushort_t Bsh[2][4096];
  const int tid = threadIdx.x;
  const int w = tid >> 6, l = tid & 63;
  const int wr = w >> 1, wc = w & 1;
  const int crow = l >> 3;
  const int ksw = ((l & 7) ^ crow) * 8;

  const ushort_t* Ap[2];
  const ushort_t* Bp[2];
  int loff[2];
#pragma unroll
  for (int c = 0; c < 2; ++c) {
    int chunk = w * 2 + c;  // 0..7
    Ap[c] = wbT + (size_t)(kt * 64 + chunk * 8 + crow) * 4096 + b * 512 + ms * 64 + ksw;
    Bp[c] = YcT + (size_t)(dt * 64 + chunk * 8 + crow) * 4096 + b * 512 + ms * 64 + ksw;
    loff[c] = chunk * 512;
  }

  f32x4 acc[2][2];
#pragma unroll
  for (int i = 0; i < 2; ++i)
#pragma unroll
    for (int j = 0; j < 2; ++j) acc[i][j] = (f32x4){0.f, 0.f, 0.f, 0.f};

  const int sw = l & 7, qq = l >> 4;

#define STAGE6(buf, g)                                                       \
  {                                                                          \
    size_t offA = (size_t)(g)*524288;                                        \
    size_t offB = (size_t)(g)*1048576;                                       \
    gload_lds16(Ap[0] + offA, &Ash[buf][loff[0]]);                           \
    gload_lds16(Ap[1] + offA, &Ash[buf][loff[1]]);                           \
    gload_lds16(Bp[0] + offB, &Bsh[buf][loff[0]]);                           \
    gload_lds16(Bp[1] + offB, &Bsh[buf][loff[1]]);                           \
  }

#define COMPUTE6(buf)                                                                    \
  {                                                                                      \
    s16x8 af[2][2], bf[2][2];                                                            \
    _Pragma("unroll") for (int kk = 0; kk < 2; ++kk) {                                   \
      int slot = (((kk << 2) + qq) ^ sw) * 8;                                            \
      _Pragma("unroll") for (int mi = 0; mi < 2; ++mi) {                                 \
        af[mi][kk] = *(const s16x8*)&Ash[buf][(wr * 32 + mi * 16 + (l & 15)) * 64 +      \
                                             slot];                                     \
        bf[mi][kk] = *(const s16x8*)&Bsh[buf][(wc * 32 + mi * 16 + (l & 15)) * 64 +      \
                                             slot];                                     \
      }                                                                                  \
    }                                                                                    \
    _Pragma("unroll") for (int kk = 0; kk < 2; ++kk)                                     \
        _Pragma("unroll") for (int mi = 0; mi < 2; ++mi)                                 \
            _Pragma("unroll") for (int ni = 0; ni < 2; ++ni)                             \
                acc[mi][ni] = __builtin_amdgcn_mfma_f32_16x16x32_bf16(af[mi][kk],        \
                                                                     bf[ni][kk],        \
                                                                     acc[mi][ni], 0, 0, 0); \
  }

  STAGE6(0, 0);
  int buf = 0;
  for (int s = 0; s < 7; ++s) {  // 8 steps: one per g
    STAGE6(buf ^ 1, s + 1);
    asm volatile("s_waitcnt vmcnt(4)" ::: "memory");
    __builtin_amdgcn_s_barrier();
    asm volatile("" ::: "memory");
    COMPUTE6(buf);
    asm volatile("" ::: "memory");
    __builtin_amdgcn_s_barrier();
    buf ^= 1;
  }
  asm volatile("s_waitcnt vmcnt(0)" ::: "memory");
  __builtin_amdgcn_s_barrier();
  asm volatile("" ::: "memory");
  COMPUTE6(buf);
#undef STAGE6
#undef COMPUTE6

#pragma unroll
  for (int mi = 0; mi < 2; ++mi) {
    int row = kt * 64 + wr * 32 + mi * 16 + (l >> 4) * 4;
#pragma unroll
    for (int ni = 0; ni < 2; ++ni) {
      int col = dt * 64 + wc * 32 + ni * 16 + (l & 15);
#pragma unroll
      for (int r = 0; r < 4; ++r)
        vpart[((size_t)(ms * 8 + b) * 128 + row + r) * 256 + col] = acc[mi][ni][r];
    }
  }
}

// ---------------- K7: combine 8 partials + bias-part - S*centroid, intra-normalize ----------------
__global__ void k7_intranorm(const float* __restrict__ vpart, const float* __restrict__ colsumW,
                             const float* __restrict__ b_inp, const float* __restrict__ cent,
                             float* __restrict__ out, float* __restrict__ ss1) {
  int k = blockIdx.x;
  int b = blockIdx.y;
  int d = threadIdx.x;
  float S = 0.f, bp = 0.f;
#pragma unroll
  for (int g = 0; g < 8; ++g) {
    float cw = colsumW[b * 1024 + g * 128 + k];
    S += cw;
    bp = fmaf(b_inp[g * 256 + d], cw, bp);
  }
  size_t off = ((size_t)b * 128 + k) * 256 + d;
  float v = bp - S * cent[(size_t)k * 256 + d];
#pragma unroll
  for (int i = 0; i < 8; ++i) v += vpart[off + (size_t)i * 262144];
  float ss = v * v;
#pragma unroll
  for (int m = 1; m < 64; m <<= 1) ss += __shfl_xor(ss, m, 64);
  __shared__ float red[4];
  int lane = d & 63, wv = d >> 6;
  if (lane == 0) red[wv] = ss;
  __syncthreads();
  float tot = red[0] + red[1] + red[2] + red[3];
  float rinv = 1.0f / fmaxf(sqrtf(tot), EPSN);
  out[off] = v * rinv;
  if (d == 0) ss1[b * 128 + k] = tot * rinv * rinv;
}

// ---------------- K8: final global L2 norm ----------------
__global__ void k8_finalnorm(const float* __restrict__ ss1, float* __restrict__ out) {
  int b = blockIdx.x;
  int t = threadIdx.x;
  __shared__ float red[256];
  red[t] = (t < 128) ? ss1[b * 128 + t] : 0.f;
  __syncthreads();
  for (int o = 128; o > 0; o >>= 1) {
    if (t < o) red[t] += red[t + o];
    __syncthreads();
  }
  float rinv = 1.0f / fmaxf(sqrtf(red[0]), EPSN);
  float* op = out + (size_t)b * 32768;
  for (int i = t; i < 32768; i += 256) op[i] *= rinv;
}

extern "C" void kernel_launch(void* const* d_in, const int* in_sizes, int n_in,
                              void* d_out, int out_size, void* d_ws, size_t ws_size,
                              hipStream_t stream) {
  const float* x     = (const float*)d_in[0];
  const float* W_inp = (const float*)d_in[1];
  const float* b_inp = (const float*)d_in[2];
  const float* W_g   = (const float*)d_in[3];
  const float* b_g   = (const float*)d_in[4];
  const float* W_gk  = (const float*)d_in[5];
  // b_gk (d_in[6]) cancels in the token-axis softmax — unused.
  const float* cent  = (const float*)d_in[7];
  float* out = (float*)d_out;
  float* ws = (float*)d_ws;

  // workspace layout (float offsets), total 13,018,176 floats = 52.07 MB
  float* ssq8    = ws + 0;         // 32768
  float* colsumW = ws + 32768;     // 8192
  float* ss1     = ws + 40960;     // 1024
  float* bWg     = ws + 41984;     // 64
  __hip_bfloat16* xnb = (__hip_bfloat16*)(ws + 42048);    // 2097152 float-slots [4096][1024]
  ushort_t* wbT  = (ushort_t*)xnb;                        // alias (xnb dead after GEMM1)
  __hip_bfloat16* Wib  = (__hip_bfloat16*)(ws + 2139200); // 1048576 float-slots [2048][1024]
  __hip_bfloat16* Wgkx = (__hip_bfloat16*)(ws + 3187776); // 1179648 float-slots [1152][2048]
  float* vpart   = ws + 2139200;   // 2097152, aliases Wib+Wgkx (both dead before k6)
  __hip_bfloat16* Ycb  = (__hip_bfloat16*)(ws + 4367424); // 2097152 float-slots [4096][2048]
  ushort_t* YcT  = (ushort_t*)(ws + 6464576);             // 4194304 float-slots [2048][4096]
  ushort_t* logitsTb = (ushort_t*)(ws + 10658880);        // 2359296 float-slots [1152][4096] bf16

  k0_ssq<<<512, 256, 0, stream>>>(x, ssq8);
  k1_transpose<<<dim3(16, 64), 256, 0, stream>>>(x, ssq8, xnb);
  kpack2<<<4360, 256, 0, stream>>>(W_inp, W_gk, W_g, b_inp, b_g, Wib, Wgkx, bWg);
  // GEMM1: Ycb[4096,2048] = xnb @ Wib^T ; epilogue also writes YcT[2048][4096]
  gemm_bf16_nt_db<0><<<dim3(16, 32), 512, 0, stream>>>((const ushort_t*)xnb, (const ushort_t*)Wib,
                                                       (ushort_t*)Ycb, nullptr, YcT, 1024, 2048);
  // GEMM2: logitsTb[1152,4096] = Wgkx @ Ycb^T (bf16 out; rows 1024-1031 = gate logits)
  gemm_bf16_nt_db<2><<<dim3(32, 9), 512, 0, stream>>>((const ushort_t*)Wgkx, (const ushort_t*)Ycb,
                                                      logitsTb, nullptr, nullptr, 2048, 4096);
  k5_softmax<<<2048, 256, 0, stream>>>(logitsTb, bWg, colsumW, wbT);
  k6_vlad_mfma<<<dim3(8, 8, 8), 256, 0, stream>>>(wbT, YcT, vpart);
  k7_intranorm<<<dim3(128, 8), 256, 0, stream>>>(vpart, colsumW, b_inp, cent, out, ss1);
  k8_finalnorm<<<8, 256, 0, stream>>>(ss1, out);
}